// Round 13
// baseline (5841.383 us; speedup 1.0000x reference)
//
#include <hip/hip_runtime.h>
#include <cstdint>
#include <cstddef>

#define TOK    4096
#define SEQL   2048
#define DMODEL 768
#define NLAYER 12
#define DSTATE 128
#define HEADD  64
#define DINNER 1536
#define NHEADS 24
#define CONVD  1792
#define DIPROJ 3352
#define DIPAD  3456
#define DFF    2048
#define VOCABN 32000
#define NCHUNK 16
#define CHUNKL 128
#define CTS    8

typedef __attribute__((ext_vector_type(8))) short bf16x8;
typedef __attribute__((ext_vector_type(4))) float f32x4;

__device__ __forceinline__ unsigned short f2bf(float f) {
  union { float f; unsigned u; } v; v.f = f;
  return (unsigned short)((v.u + 0x7FFFu + ((v.u >> 16) & 1u)) >> 16);
}

__device__ __forceinline__ void gld16(const void* g, void* l) {
  __builtin_amdgcn_global_load_lds(
      (const __attribute__((address_space(1))) unsigned int*)g,
      (__attribute__((address_space(3))) unsigned int*)l, 16, 0, 0);
}

// streaming store: bypass L2/L3 allocation (sc0 sc1 nt) — logits are never re-read
__device__ __forceinline__ void stream_store(float* addr, float v) {
  asm volatile("global_store_dword %0, %1, off sc0 sc1 nt" :: "v"(addr), "v"(v) : "memory");
}

// ---------------- block reductions (template wave count) ----------------
template <int NW>
__device__ __forceinline__ void red2t(float& a, float& b) {
#pragma unroll
  for (int o = 1; o < 64; o <<= 1) { a += __shfl_xor(a, o, 64); b += __shfl_xor(b, o, 64); }
  __shared__ float sa[NW], sb[NW];
  const int w = threadIdx.x >> 6;
  if ((threadIdx.x & 63) == 0) { sa[w] = a; sb[w] = b; }
  __syncthreads();
  a = sa[0]; b = sb[0];
#pragma unroll
  for (int i = 1; i < NW; ++i) { a += sa[i]; b += sb[i]; }
}

template <int NW>
__device__ __forceinline__ float red1t(float a) {
#pragma unroll
  for (int o = 1; o < 64; o <<= 1) a += __shfl_xor(a, o, 64);
  __shared__ float sa[NW];
  const int w = threadIdx.x >> 6;
  if ((threadIdx.x & 63) == 0) sa[w] = a;
  __syncthreads();
  float r = sa[0];
#pragma unroll
  for (int i = 1; i < NW; ++i) r += sa[i];
  return r;
}

// ---------------- GEMM: C[m,n] = sum_k A[m,k]*B[n,k], bf16 in / f32 out ----------------
// Round-13: 3-buffer LDS ring, depth-2-ahead counted pipeline. Intra-K-step order is
// EXACTLY round-9/12's proven structure (vmcnt -> barrier -> ds_reads -> lgkmcnt(0)
// +sched_barrier -> barrier -> stage BEFORE MFMA -> MFMA); only the ring depth and
// vmcnt count change: each stage now has TWO K-steps (~600cyc) to land before its
// vmcnt(2*LPS), covering L2 latency. LDS: big 72KB (2 blk/CU), small 36KB ((256,3);
// VGPR ~80 << 170 budget — NOT the round-11 spill trap). K-order bit-identical.
// EPI: 0 = store C; 1 = store C+R; 2 = silu-gate pair -> bf16 Cg (w12 fused);
//      3 = streaming store (LM head).
template <int EPI, int BM, int BN>
__global__ __launch_bounds__(256, (BM == 256 ? 2 : 3)) void gemm_bt(
    const unsigned short* __restrict__ A, const unsigned short* __restrict__ B,
    float* __restrict__ C, unsigned short* __restrict__ Cg,
    const float* __restrict__ R, int M, int N, int K) {
  constexpr int WM  = BM / 2, WN = BN / 2;
  constexpr int MFR = WM / 16, NFR = WN / 16;
  constexpr int LPS = (BM == 256 ? 4 : BM == 128 ? 2 : 1) + (BN == 128 ? 2 : 1);
  __shared__ unsigned short lA[3][BM * 32];
  __shared__ unsigned short lB[3][BN * 32];

  int lid = (int)blockIdx.x;
  {
    const int nwg = (int)gridDim.x;
    const int xcd = lid & 7;
    const int q = nwg >> 3, r = nwg & 7;
    const int b2 = (xcd < r) ? xcd * (q + 1) : r * (q + 1) + (xcd - r) * q;
    lid = b2 + (lid >> 3);
  }
  const int mtiles = M / BM;
  int m0, n0;
  if constexpr (BM >= 128 && BN == 128) {
    constexpr int GRP = (BM == 256) ? 8 : 16;     // 2048-row stripe (3.1 MB @K=768)
    const int nt = (int)gridDim.x / mtiles;
    const int span = GRP * nt;
    const int g = lid / span, rem = lid % span;
    m0 = (g * GRP + (rem % GRP)) * BM;
    n0 = (rem / GRP) * BN;
  } else {
    m0 = (lid % mtiles) * BM;
    n0 = (lid / mtiles) * BN;
  }

  const int tid = threadIdx.x, wave = tid >> 6, lane = tid & 63;
  const int wr = (wave >> 1) * WM, wc = (wave & 1) * WN;
  const int srow = lane >> 2;
  const int scol = (((lane & 3) ^ ((lane >> 3) & 3))) * 8;  // pre-swizzled source chunk
  const int rdk  = ((lane >> 4) ^ ((lane >> 1) & 3)) * 8;   // swizzled read chunk

  f32x4 acc[MFR][NFR];
#pragma unroll
  for (int i = 0; i < MFR; ++i)
#pragma unroll
    for (int j = 0; j < NFR; ++j) acc[i][j] = (f32x4){0.f, 0.f, 0.f, 0.f};

  const size_t arow0 = (size_t)(m0 + (BM == 256 ? wave * 64 : BM == 128 ? wave * 32 : wave * 16) + srow) * K + scol;
  const size_t brow0 = (size_t)(n0 + (BN == 128 ? wave * 32 : wave * 16) + srow) * K + scol;

  auto stage = [&](int buf, int k0) {
    if constexpr (BM == 256) {
#pragma unroll
      for (int j = 0; j < 4; ++j)
        gld16(A + arow0 + (size_t)(j * 16) * K + k0, lA[buf] + (wave * 4 + j) * 512);
    } else if constexpr (BM == 128) {
      gld16(A + arow0 + k0,                  lA[buf] + (wave * 2 + 0) * 512);
      gld16(A + arow0 + (size_t)16 * K + k0, lA[buf] + (wave * 2 + 1) * 512);
    } else {
      gld16(A + arow0 + k0, lA[buf] + wave * 512);
    }
    if constexpr (BN == 128) {
      gld16(B + brow0 + k0,                  lB[buf] + (wave * 2 + 0) * 512);
      gld16(B + brow0 + (size_t)16 * K + k0, lB[buf] + (wave * 2 + 1) * 512);
    } else {
      gld16(B + brow0 + k0, lB[buf] + wave * 512);
    }
  };

  // depth-2-ahead prologue: three stages in flight (K >= 768 always: k=0,32,64 valid)
  stage(0, 0);
  stage(1, 32);
  stage(2, 64);
  int cur = 0;
  for (int k0 = 0; k0 < K; k0 += 32) {
    // oldest stage (buffer cur, tile k0) complete; the TWO newer stages stay in flight
    asm volatile("s_waitcnt vmcnt(%0)" :: "i"(2 * LPS) : "memory");
    __builtin_amdgcn_s_barrier();
    bf16x8 af[MFR], bfr[NFR];
#pragma unroll
    for (int mi = 0; mi < MFR; ++mi) {
      const int ra = wr + mi * 16 + (lane & 15);
      af[mi] = *(const bf16x8*)&lA[cur][ra * 32 + rdk];
    }
#pragma unroll
    for (int ni = 0; ni < NFR; ++ni) {
      const int rb = wc + ni * 16 + (lane & 15);
      bfr[ni] = *(const bf16x8*)&lB[cur][rb * 32 + rdk];
    }
    asm volatile("s_waitcnt lgkmcnt(0)" ::: "memory");
    __builtin_amdgcn_sched_barrier(0);
    __builtin_amdgcn_s_barrier();          // all waves done reading `cur`
    if (k0 + 96 < K) stage(cur, k0 + 96);  // overwrite cur with tile k+3 (2 K-steps of lead)
    __builtin_amdgcn_sched_barrier(0);     // keep load issue ahead of MFMA cluster
#pragma unroll
    for (int mi = 0; mi < MFR; ++mi)
#pragma unroll
      for (int ni = 0; ni < NFR; ++ni)
        acc[mi][ni] = __builtin_amdgcn_mfma_f32_16x16x32_bf16(af[mi], bfr[ni], acc[mi][ni], 0, 0, 0);
    cur = (cur == 2) ? 0 : cur + 1;
  }

  const int er = (lane >> 4) * 4, ec = lane & 15;
#pragma unroll
  for (int mi = 0; mi < MFR; ++mi) {
#pragma unroll
    for (int r = 0; r < 4; ++r) {
      const size_t row = (size_t)(m0 + wr + mi * 16 + er + r);
#pragma unroll
      for (int ni = 0; ni < NFR; ++ni) {
        float v = acc[mi][ni][r];
        const int col = n0 + wc + ec + ni * 16;
        if constexpr (EPI == 2) {
          const float o = __shfl_xor(v, 1, 64);
          if ((lane & 1) == 0)
            Cg[row * DFF + (col >> 1)] = f2bf((v / (1.f + expf(-v))) * o);
        } else if constexpr (EPI == 1) {
          C[row * N + col] = v + R[row * N + col];
        } else if constexpr (EPI == 3) {
          stream_store(&C[row * N + col], v);
        } else {
          C[row * N + col] = v;
        }
      }
    }
  }
}

// ---------------- conversions ----------------
__global__ __launch_bounds__(256) void cvt_k(const float* __restrict__ in, unsigned short* __restrict__ out, long n) {
  const long i = ((long)blockIdx.x * 256 + threadIdx.x) * 4;
  if (i >= n) return;
  const float4 v = *(const float4*)(in + i);
  ushort4 o; o.x = f2bf(v.x); o.y = f2bf(v.y); o.z = f2bf(v.z); o.w = f2bf(v.w);
  *(ushort4*)(out + i) = o;
}

__global__ __launch_bounds__(256) void cvt_inw_k(const float* __restrict__ in, unsigned short* __restrict__ out) {
  const int row = blockIdx.x;
  const int l = row / DIPAD, n = row % DIPAD;
  unsigned short* orow = out + (size_t)row * DMODEL;
  if (n >= DIPROJ) {
    for (int c = threadIdx.x; c < DMODEL; c += 256) orow[c] = 0;
    return;
  }
  const float* irow = in + ((size_t)l * DIPROJ + n) * DMODEL;
  for (int c = threadIdx.x; c < DMODEL; c += 256) orow[c] = f2bf(irow[c]);
}

// w1,w2 [L][DFF][DMODEL] -> interleaved w12 [L][2*DFF][DMODEL]: row 2f = w1[f], 2f+1 = w2[f]
__global__ __launch_bounds__(256) void cvt_w12_k(const float* __restrict__ w1, const float* __restrict__ w2,
                                                 unsigned short* __restrict__ out) {
  const int row = blockIdx.x;
  const int l = row / (2 * DFF), rr = row % (2 * DFF);
  const int f = rr >> 1;
  const float* irow = ((rr & 1) == 0) ? (w1 + ((size_t)l * DFF + f) * DMODEL)
                                      : (w2 + ((size_t)l * DFF + f) * DMODEL);
  unsigned short* orow = out + (size_t)row * DMODEL;
  for (int c = threadIdx.x; c < DMODEL; c += 256) orow[c] = f2bf(irow[c]);
}

// ---------------- elementwise / norms (vectorized, G13) ----------------
__global__ __launch_bounds__(192) void embed_k(const int* __restrict__ ids, const float* __restrict__ emb, float* __restrict__ h) {
  const int t = blockIdx.x;
  const float4 v = *(const float4*)(emb + (size_t)ids[t] * DMODEL + threadIdx.x * 4);
  *(float4*)(h + (size_t)t * DMODEL + threadIdx.x * 4) = v;
}

__global__ __launch_bounds__(192) void ln_k(const float* __restrict__ x, const float* __restrict__ w, const float* __restrict__ b,
                                            unsigned short* __restrict__ out) {
  const int t = blockIdx.x, c4 = threadIdx.x * 4;
  const float4 v = *(const float4*)(x + (size_t)t * DMODEL + c4);
  float s = v.x + v.y + v.z + v.w;
  float ss = v.x * v.x + v.y * v.y + v.z * v.z + v.w * v.w;
  red2t<3>(s, ss);
  const float mu = s * (1.f / DMODEL);
  const float inv = rsqrtf(ss * (1.f / DMODEL) - mu * mu + 1e-5f);
  const float4 wv = *(const float4*)(w + c4);
  const float4 bv = *(const float4*)(b + c4);
  ushort4 o;
  o.x = f2bf((v.x - mu) * inv * wv.x + bv.x);
  o.y = f2bf((v.y - mu) * inv * wv.y + bv.y);
  o.z = f2bf((v.z - mu) * inv * wv.z + bv.z);
  o.w = f2bf((v.w - mu) * inv * wv.w + bv.w);
  *(ushort4*)(out + (size_t)t * DMODEL + c4) = o;
}

// conv + SiLU, sliding-window: CTS=8 timesteps/block, register window
// (read amp 1.4x vs old 4x). Skipped taps = fmaf(w,0,acc) -> bit-identical.
__global__ __launch_bounds__(448) void conv_k(const float* __restrict__ zx, const float* __restrict__ cw, const float* __restrict__ cb,
                                              const float* __restrict__ dt_bias, const float* __restrict__ A_log,
                                              float* __restrict__ xs, float* __restrict__ Bm, float* __restrict__ Cm,
                                              float* __restrict__ dtv, float* __restrict__ dAv) {
  const int t0g = blockIdx.x * CTS;
  const int b = t0g >> 11, l0 = t0g & (SEQL - 1);
  const int c4 = threadIdx.x * 4;
  const float4 w0  = *(const float4*)(cw + c4 * 4);
  const float4 w1v = *(const float4*)(cw + c4 * 4 + 4);
  const float4 w2v = *(const float4*)(cw + c4 * 4 + 8);
  const float4 w3v = *(const float4*)(cw + c4 * 4 + 12);
  const float4 bias = *(const float4*)(cb + c4);
  float4 win[3];
#pragma unroll
  for (int j = 0; j < 3; ++j) {
    const int ll = l0 - 3 + j;
    win[j] = (ll >= 0) ? *(const float4*)(zx + (size_t)(b * SEQL + ll) * DIPAD + DINNER + c4)
                       : (float4){0.f, 0.f, 0.f, 0.f};
  }
#pragma unroll
  for (int i = 0; i < CTS; ++i) {
    const int t = t0g + i;
    const float4 cur4 = *(const float4*)(zx + (size_t)t * DIPAD + DINNER + c4);
    float4 a = bias;
    a.x = fmaf(w0.x,  win[0].x, a.x); a.y = fmaf(w1v.x, win[0].y, a.y);
    a.z = fmaf(w2v.x, win[0].z, a.z); a.w = fmaf(w3v.x, win[0].w, a.w);
    a.x = fmaf(w0.y,  win[1].x, a.x); a.y = fmaf(w1v.y, win[1].y, a.y);
    a.z = fmaf(w2v.y, win[1].z, a.z); a.w = fmaf(w3v.y, win[1].w, a.w);
    a.x = fmaf(w0.z,  win[2].x, a.x); a.y = fmaf(w1v.z, win[2].y, a.y);
    a.z = fmaf(w2v.z, win[2].z, a.z); a.w = fmaf(w3v.z, win[2].w, a.w);
    a.x = fmaf(w0.w,  cur4.x, a.x);   a.y = fmaf(w1v.w, cur4.y, a.y);
    a.z = fmaf(w2v.w, cur4.z, a.z);   a.w = fmaf(w3v.w, cur4.w, a.w);
    a.x = a.x / (1.f + expf(-a.x));
    a.y = a.y / (1.f + expf(-a.y));
    a.z = a.z / (1.f + expf(-a.z));
    a.w = a.w / (1.f + expf(-a.w));
    if (threadIdx.x < 384)      *(float4*)(xs + (size_t)t * DINNER + c4) = a;
    else if (threadIdx.x < 416) *(float4*)(Bm + (size_t)t * DSTATE + (c4 - DINNER)) = a;
    else                        *(float4*)(Cm + (size_t)t * DSTATE + (c4 - DINNER - DSTATE)) = a;
    win[0] = win[1]; win[1] = win[2]; win[2] = cur4;
  }
  if (threadIdx.x < NHEADS) {
    const int hh = threadIdx.x;
    const float eA = expf(A_log[hh]);
    const float db = dt_bias[hh];
#pragma unroll
    for (int i = 0; i < CTS; ++i) {
      const int t = t0g + i;
      const float xv = zx[(size_t)t * DIPAD + DINNER + CONVD + hh] + db;
      const float dt = (xv > 20.f) ? xv : log1pf(expf(xv));
      dtv[t * NHEADS + hh] = dt;
      dAv[t * NHEADS + hh] = expf(-dt * eA);
    }
  }
}

// ---------------- chunked SSM scan ----------------
// scan1: B/C LDS-staged in 16-step double-buffered chunks; xp prefetched to regs;
// counted vmcnt (never 0 in-loop). Split-n layout: LDS reads 2-way = free.
__global__ __launch_bounds__(256) void scan1_k(const float* __restrict__ xs, const float* __restrict__ Bm, const float* __restrict__ Cm,
                                               const float* __restrict__ dtv, const float* __restrict__ dAv,
                                               const float* __restrict__ Dp, float* __restrict__ y,
                                               float* __restrict__ Sloc, float* __restrict__ cumv) {
  __shared__ float lB[2][16][128];
  __shared__ float lC[2][16][128];
  __shared__ float sdA[2][16], sdt[2][16];
  const int pg = blockIdx.x, hh = blockIdx.y, z = blockIdx.z;
  const int b = z >> 4, c = z & (NCHUNK - 1);
  const int pl = threadIdx.x >> 4, ln = threadIdx.x & 15;
  const int p = pg * 16 + pl;
  const int wv = threadIdx.x >> 6, lane = threadIdx.x & 63;
  const float Dph = Dp[hh];
  const int bT = b * SEQL + c * CHUNKL;

  auto stage = [&](int buf, int t0) {
#pragma unroll
    for (int j = 0; j < 2; ++j) {
      const int pr = wv + 4 * j;                 // 0..7 row-pairs
      const int row = 2 * pr + (lane >> 5);      // 0..15
      gld16(Bm + (size_t)(t0 + row) * DSTATE + (lane & 31) * 4, &lB[buf][2 * pr][0]);
      gld16(Cm + (size_t)(t0 + row) * DSTATE + (lane & 31) * 4, &lC[buf][2 * pr][0]);
    }
    if (threadIdx.x < 16)      sdA[buf][threadIdx.x]      = dAv[(t0 + threadIdx.x) * NHEADS + hh];
    else if (threadIdx.x < 32) sdt[buf][threadIdx.x - 16] = dtv[(t0 + threadIdx.x - 16) * NHEADS + hh];
  };

  float s0 = 0, s1 = 0, s2 = 0, s3 = 0, s4 = 0, s5 = 0, s6 = 0, s7 = 0;
  float r = 1.f;
  int cur = 0;
  stage(0, bT);
  for (int cc = 0; cc < CHUNKL; cc += 16) {
    const int t0 = bT + cc;
    __builtin_amdgcn_s_barrier();   // all waves done reading the buffer we overwrite next
    float xq[16];
#pragma unroll
    for (int i = 0; i < 16; ++i) xq[i] = xs[(size_t)(t0 + i) * DINNER + hh * HEADD + p];
    if (cc + 16 < CHUNKL) stage(cur ^ 1, t0 + 16);
    asm volatile("s_waitcnt vmcnt(4) lgkmcnt(0)" ::: "memory");  // cur buffer + xq landed; next stage in flight
    __builtin_amdgcn_s_barrier();
#pragma unroll
    for (int i = 0; i < 16; ++i) {
      const float dAt = sdA[cur][i], dtt = sdt[cur][i];
      const float xdt = xq[i] * dtt;
      const float4 B0 = *(const float4*)&lB[cur][i][ln * 4];
      const float4 B1 = *(const float4*)&lB[cur][i][64 + ln * 4];
      const float4 C0 = *(const float4*)&lC[cur][i][ln * 4];
      const float4 C1 = *(const float4*)&lC[cur][i][64 + ln * 4];
      float yp;
      s0 = fmaf(s0, dAt, B0.x * xdt); yp = s0 * C0.x;
      s1 = fmaf(s1, dAt, B0.y * xdt); yp = fmaf(s1, C0.y, yp);
      s2 = fmaf(s2, dAt, B0.z * xdt); yp = fmaf(s2, C0.z, yp);
      s3 = fmaf(s3, dAt, B0.w * xdt); yp = fmaf(s3, C0.w, yp);
      s4 = fmaf(s4, dAt, B1.x * xdt); yp = fmaf(s4, C1.x, yp);
      s5 = fmaf(s5, dAt, B1.y * xdt); yp = fmaf(s5, C1.y, yp);
      s6 = fmaf(s6, dAt, B1.z * xdt); yp = fmaf(s6, C1.z, yp);
      s7 = fmaf(s7, dAt, B1.w * xdt); yp = fmaf(s7, C1.w, yp);
#pragma unroll
      for (int o = 1; o < 16; o <<= 1) yp += __shfl_xor(yp, o, 64);
      if (ln == 0) y[(size_t)(t0 + i) * DINNER + hh * HEADD + p] = fmaf(Dph, xq[i], yp);
      r *= dAt;
      if (threadIdx.x == 0) cumv[(size_t)(b * NHEADS + hh) * SEQL + (c * CHUNKL + cc + i)] = r;
    }
    cur ^= 1;
  }
  float* sp = Sloc + (((size_t)(b * NHEADS + hh) * NCHUNK + c) * HEADD + p) * DSTATE;
  *(float4*)(sp + ln * 4)      = (float4){s0, s1, s2, s3};
  *(float4*)(sp + 64 + ln * 4) = (float4){s4, s5, s6, s7};
}

// scan3 (scan2 fused): each block recomputes S_in[c] from Sloc slots 0..c-1 with the
// SAME fold order the old scan2 used (acc = P_j*acc + Sloc[j-1]) -> bit-identical.
// C LDS-staged (double-buffered 16-step chunks), y prefetched to regs.
__global__ __launch_bounds__(256) void scan3_k(const float* __restrict__ Cm, const float* __restrict__ cumv,
                                               const float* __restrict__ Sloc, float* __restrict__ y) {
  __shared__ float lC[2][16][128];
  __shared__ float sCum[2][16];
  const int pg = blockIdx.x, hh = blockIdx.y, z = blockIdx.z;
  const int b = z / (NCHUNK - 1), c = z % (NCHUNK - 1) + 1;
  const int pl = threadIdx.x >> 4, ln = threadIdx.x & 15;
  const int p = pg * 16 + pl;
  const int wv = threadIdx.x >> 6, lane = threadIdx.x & 63;
  const int bT = b * SEQL + c * CHUNKL;

  // inline inter-chunk combine (was scan2_k)
  float4 sA = (float4){0.f, 0.f, 0.f, 0.f}, sB = (float4){0.f, 0.f, 0.f, 0.f};
  {
    const float* spb = Sloc + ((size_t)(b * NHEADS + hh) * NCHUNK) * (HEADD * DSTATE) + (size_t)p * DSTATE;
    for (int j = 1; j <= c; ++j) {
      const float Pj = cumv[(size_t)(b * NHEADS + hh) * SEQL + j * CHUNKL - 1];
      const float* sj = spb + (size_t)(j - 1) * (HEADD * DSTATE);
      const float4 v0 = *(const float4*)(sj + ln * 4);
      const float4 v1 = *(const float4*)(sj + 64 + ln * 4);
      sA.x = fmaf(Pj, sA.x, v0.x); sA.y = fmaf(Pj, sA.y, v0.y);
      sA.z = fmaf(Pj, sA.z, v0.z); sA.w = fmaf(Pj, sA.w, v0.w);
      sB.x = fmaf(Pj, sB.x, v1.x); sB.y = fmaf(Pj, sB.y, v1.y);
      sB.z = fmaf(Pj, sB.z, v1.z); sB.w = fmaf(Pj, sB.w, v1.w);
    }
  }

  auto stage = [&](int buf, int t0) {
#pragma unroll
    for (int j = 0; j < 2; ++j) {
      const int pr = wv + 4 * j;
      const int row = 2 * pr + (lane >> 5);
      gld16(Cm + (size_t)(t0 + row) * DSTATE + (lane & 31) * 4, &lC[buf][2 * pr][0]);
    }
    if (threadIdx.x < 16)
      sCum[buf][threadIdx.x] = cumv[(size_t)(b * NHEADS + hh) * SEQL + (t0 - b * SEQL) + threadIdx.x];
  };

  int cur = 0;
  stage(0, bT);
  for (int cc = 0; cc < CHUNKL; cc += 16) {
    const int t0 = bT + cc;
    __builtin_amdgcn_s_barrier();
    float yq[16];
#pragma unroll
    for (int i = 0; i < 16; ++i) yq[i] = y[(size_t)(t0 + i) * DINNER + hh * HEADD + p];
    if (cc + 16 < CHUNKL) stage(cur ^ 1, t0 + 16);
    asm volatile("s_waitcnt vmcnt(2) lgkmcnt(0)" ::: "memory");
    __builtin_amdgcn_s_barrier();
#pragma unroll
    for (int i = 0; i < 16; ++i) {
      const float4 C0 = *(const float4*)&lC[cur][i][ln * 4];
      const float4 C1 = *(const float4*)&lC[cur][i][64 + ln * 4];
      float yp = sA.x * C0.x;
      yp = fmaf(sA.y, C0.y, yp);
      yp = fmaf(sA.z, C0.z, yp);
      yp = fmaf(sA.w, C0.w, yp);
      yp = fmaf(sB.x, C1.x, yp);
      yp = fmaf(sB.y, C1.y, yp);
      yp = fmaf(sB.z, C1.z, yp);
      yp = fmaf(sB.w, C1.w, yp);
#pragma unroll
      for (int o = 1; o < 16; o <<= 1) yp += __shfl_xor(yp, o, 64);
      if (ln == 0) y[(size_t)(t0 + i) * DINNER + hh * HEADD + p] = fmaf(sCum[cur][i], yp, yq[i]);
    }
    cur ^= 1;
  }
}

__global__ __launch_bounds__(384) void grms_k(const float* __restrict__ y, const float* __restrict__ zx,
                                              const float* __restrict__ rw, unsigned short* __restrict__ out) {
  const int t = blockIdx.x, c4 = threadIdx.x * 4;
  const float4 yv = *(const float4*)(y + (size_t)t * DINNER + c4);
  const float4 zv = *(const float4*)(zx + (size_t)t * DIPAD + c4);
  float4 g;
  g.x = yv.x * (zv.x / (1.f + expf(-zv.x)));
  g.y = yv.y * (zv.y / (1.f + expf(-zv.y)));
  g.z = yv.z * (zv.z / (1.f + expf(-zv.z)));
  g.w = yv.w * (zv.w / (1.f + expf(-zv.w)));
  float ss = g.x * g.x + g.y * g.y + g.z * g.z + g.w * g.w;
  ss = red1t<6>(ss);
  const float inv = rsqrtf(ss * (1.f / DINNER) + 1e-5f);
  const float4 rv = *(const float4*)(rw + c4);
  ushort4 o;
  o.x = f2bf(g.x * inv * rv.x);
  o.y = f2bf(g.y * inv * rv.y);
  o.z = f2bf(g.z * inv * rv.z);
  o.w = f2bf(g.w * inv * rv.w);
  *(ushort4*)(out + (size_t)t * DINNER + c4) = o;
}

// ---------------- host orchestration ----------------
extern "C" void kernel_launch(void* const* d_in, const int* in_sizes, int n_in,
                              void* d_out, int out_size, void* d_ws, size_t ws_size,
                              hipStream_t stream) {
  const int*   ids      = (const int*)  d_in[0];
  const float* emb      = (const float*)d_in[1];
  const float* ln_w     = (const float*)d_in[2];
  const float* ln_b     = (const float*)d_in[3];
  const float* in_w     = (const float*)d_in[4];
  const float* conv_w   = (const float*)d_in[5];
  const float* conv_b   = (const float*)d_in[6];
  const float* dt_bias  = (const float*)d_in[7];
  const float* A_log    = (const float*)d_in[8];
  const float* Dp       = (const float*)d_in[9];
  const float* rms_w    = (const float*)d_in[10];
  const float* out_w    = (const float*)d_in[11];
  const float* mlp_ln_w = (const float*)d_in[12];
  const float* mlp_ln_b = (const float*)d_in[13];
  const float* w1       = (const float*)d_in[14];
  const float* w2       = (const float*)d_in[15];
  const float* w3       = (const float*)d_in[16];
  const float* normf_w  = (const float*)d_in[17];
  const float* normf_b  = (const float*)d_in[18];
  const float* lm_w     = (const float*)d_in[19];

  char* base = (char*)d_ws;
  size_t off = 0;
  auto alloc = [&](size_t bytes) -> char* {
    char* p = base + off;
    off += (bytes + 255) & ~(size_t)255;
    return p;
  };
  float* h             = (float*)alloc((size_t)TOK * DMODEL * 4);
  unsigned short* xn   = (unsigned short*)alloc((size_t)TOK * DMODEL * 2);
  float* zx            = (float*)alloc((size_t)TOK * DIPAD * 4);
  float* xs            = (float*)alloc((size_t)TOK * DINNER * 4);
  float* Bm            = (float*)alloc((size_t)TOK * DSTATE * 4);
  float* Cm            = (float*)alloc((size_t)TOK * DSTATE * 4);
  float* dtv           = (float*)alloc((size_t)TOK * NHEADS * 4);
  float* dAv           = (float*)alloc((size_t)TOK * NHEADS * 4);
  float* y             = (float*)alloc((size_t)TOK * DINNER * 4);
  unsigned short* ybf  = (unsigned short*)alloc((size_t)TOK * DINNER * 2);
  float* hf            = (float*)alloc((size_t)TOK * DMODEL * 4);
  unsigned short* gbf  = (unsigned short*)alloc((size_t)TOK * DMODEL * 2);
  unsigned short* gate = (unsigned short*)alloc((size_t)TOK * DFF * 2);
  float* Sloc          = (float*)alloc((size_t)2 * NHEADS * NCHUNK * HEADD * DSTATE * 4);
  float* cumv          = (float*)alloc((size_t)2 * NHEADS * SEQL * 4);
  unsigned short* inw_bf  = (unsigned short*)alloc((size_t)NLAYER * DIPAD * DMODEL * 2);
  unsigned short* outw_bf = (unsigned short*)alloc((size_t)NLAYER * DMODEL * DINNER * 2);
  unsigned short* w12_bf  = (unsigned short*)alloc((size_t)NLAYER * 2 * DFF * DMODEL * 2);
  unsigned short* w3_bf   = (unsigned short*)alloc((size_t)NLAYER * DMODEL * DFF * 2);
  unsigned short* lm_bf   = (unsigned short*)alloc((size_t)VOCABN * DMODEL * 2);
  if (off > ws_size) return;

  cvt_inw_k<<<NLAYER * DIPAD, 256, 0, stream>>>(in_w, inw_bf);
  cvt_w12_k<<<NLAYER * 2 * DFF, 256, 0, stream>>>(w1, w2, w12_bf);
  {
    const long n1 = (long)NLAYER * DMODEL * DINNER;
    cvt_k<<<(unsigned)((n1 + 1023) / 1024), 256, 0, stream>>>(out_w, outw_bf, n1);
    const long n3 = (long)NLAYER * DMODEL * DFF;
    cvt_k<<<(unsigned)((n3 + 1023) / 1024), 256, 0, stream>>>(w3, w3_bf, n3);
    const long n4 = (long)VOCABN * DMODEL;
    cvt_k<<<(unsigned)((n4 + 1023) / 1024), 256, 0, stream>>>(lm_w, lm_bf, n4);
  }

  embed_k<<<TOK, 192, 0, stream>>>(ids, emb, h);

  for (int l = 0; l < NLAYER; ++l) {
    ln_k<<<TOK, 192, 0, stream>>>(h, ln_w + l * DMODEL, ln_b + l * DMODEL, xn);
    gemm_bt<0, 256, 128><<<(TOK / 256) * (DIPAD / 128), 256, 0, stream>>>(
        xn, inw_bf + (size_t)l * DIPAD * DMODEL, zx, nullptr, nullptr, TOK, DIPAD, DMODEL);
    conv_k<<<TOK / CTS, 448, 0, stream>>>(zx, conv_w + (size_t)l * CONVD * 4, conv_b + (size_t)l * CONVD,
                                          dt_bias + l * NHEADS, A_log + l * NHEADS, xs, Bm, Cm, dtv, dAv);
    scan1_k<<<dim3(4, NHEADS, 2 * NCHUNK), 256, 0, stream>>>(xs, Bm, Cm, dtv, dAv, Dp + l * NHEADS, y, Sloc, cumv);
    scan3_k<<<dim3(4, NHEADS, 2 * (NCHUNK - 1)), 256, 0, stream>>>(Cm, cumv, Sloc, y);
    grms_k<<<TOK, 384, 0, stream>>>(y, zx, rms_w + (size_t)l * DINNER, ybf);
    gemm_bt<1, 128, 64><<<(TOK / 128) * (DMODEL / 64), 256, 0, stream>>>(
        ybf, outw_bf + (size_t)l * DMODEL * DINNER, hf, nullptr, h, TOK, DMODEL, DINNER);
    ln_k<<<TOK, 192, 0, stream>>>(hf, mlp_ln_w + l * DMODEL, mlp_ln_b + l * DMODEL, gbf);
    gemm_bt<2, 256, 128><<<(TOK / 256) * (2 * DFF / 128), 256, 0, stream>>>(
        gbf, w12_bf + (size_t)l * 2 * DFF * DMODEL, nullptr, gate, nullptr, TOK, 2 * DFF, DMODEL);
    gemm_bt<1, 128, 64><<<(TOK / 128) * (DMODEL / 64), 256, 0, stream>>>(
        gate, w3_bf + (size_t)l * DMODEL * DFF, h, nullptr, hf, TOK, DMODEL, DFF);
  }

  ln_k<<<TOK, 192, 0, stream>>>(h, normf_w, normf_b, xn);
  gemm_bt<3, 256, 128><<<(TOK / 256) * (VOCABN / 128), 256, 0, stream>>>(
      xn, lm_bf, (float*)d_out, nullptr, nullptr, TOK, VOCABN, DMODEL);
}

// Round 14
// 5776.732 us; speedup vs baseline: 1.0112x; 1.0112x over previous
//
#include <hip/hip_runtime.h>
#include <cstdint>
#include <cstddef>

#define TOK    4096
#define SEQL   2048
#define DMODEL 768
#define NLAYER 12
#define DSTATE 128
#define HEADD  64
#define DINNER 1536
#define NHEADS 24
#define CONVD  1792
#define DIPROJ 3352
#define DIPAD  3456
#define DFF    2048
#define VOCABN 32000
#define NCHUNK 16
#define CHUNKL 128
#define CTS    8

typedef __attribute__((ext_vector_type(8))) short bf16x8;
typedef __attribute__((ext_vector_type(4))) float f32x4;

__device__ __forceinline__ unsigned short f2bf(float f) {
  union { float f; unsigned u; } v; v.f = f;
  return (unsigned short)((v.u + 0x7FFFu + ((v.u >> 16) & 1u)) >> 16);
}

__device__ __forceinline__ void gld16(const void* g, void* l) {
  __builtin_amdgcn_global_load_lds(
      (const __attribute__((address_space(1))) unsigned int*)g,
      (__attribute__((address_space(3))) unsigned int*)l, 16, 0, 0);
}

// streaming store: bypass L2/L3 allocation (sc0 sc1 nt) — logits are never re-read
__device__ __forceinline__ void stream_store(float* addr, float v) {
  asm volatile("global_store_dword %0, %1, off sc0 sc1 nt" :: "v"(addr), "v"(v) : "memory");
}

// ---------------- block reductions (template wave count) ----------------
template <int NW>
__device__ __forceinline__ void red2t(float& a, float& b) {
#pragma unroll
  for (int o = 1; o < 64; o <<= 1) { a += __shfl_xor(a, o, 64); b += __shfl_xor(b, o, 64); }
  __shared__ float sa[NW], sb[NW];
  const int w = threadIdx.x >> 6;
  if ((threadIdx.x & 63) == 0) { sa[w] = a; sb[w] = b; }
  __syncthreads();
  a = sa[0]; b = sb[0];
#pragma unroll
  for (int i = 1; i < NW; ++i) { a += sa[i]; b += sb[i]; }
}

template <int NW>
__device__ __forceinline__ float red1t(float a) {
#pragma unroll
  for (int o = 1; o < 64; o <<= 1) a += __shfl_xor(a, o, 64);
  __shared__ float sa[NW];
  const int w = threadIdx.x >> 6;
  if ((threadIdx.x & 63) == 0) sa[w] = a;
  __syncthreads();
  float r = sa[0];
#pragma unroll
  for (int i = 1; i < NW; ++i) r += sa[i];
  return r;
}

// ---------------- GEMM: C[m,n] = sum_k A[m,k]*B[n,k], bf16 in / f32 out ----------------
// EXACT round-12 proven structure (best measured; r13's 3-ring was neutral):
// 2-buffer ring, K-step = vmcnt(LPS) -> barrier -> ds_reads -> lgkmcnt(0)
// +sched_barrier -> barrier -> stage(cur,k+2) BEFORE MFMA -> MFMA. (256,2) is
// load-bearing (r11: (256,3) spilled the acc tile). K-order bit-identical.
// EPI: 0 = store C; 1 = store C+R; 2 = silu-gate pair -> bf16 Cg (w12 fused);
//      3 = streaming store (LM head);
//      4 = split-K=2 partial store (out_proj/w3: N=768 gives only 384 blocks =
//          1.5 blk/CU occupancy starvation; split doubles grid to 768. Each half
//          accumulates its contiguous K-range in the original order; red_k joins).
template <int EPI, int BM, int BN>
__global__ __launch_bounds__(256, 2) void gemm_bt(
    const unsigned short* __restrict__ A, const unsigned short* __restrict__ B,
    float* __restrict__ C, unsigned short* __restrict__ Cg,
    const float* __restrict__ R, int M, int N, int K) {
  constexpr int WM  = BM / 2, WN = BN / 2;
  constexpr int MFR = WM / 16, NFR = WN / 16;
  constexpr int LPS = (BM == 256 ? 4 : BM == 128 ? 2 : 1) + (BN == 128 ? 2 : 1);
  __shared__ unsigned short lA[2][BM * 32];
  __shared__ unsigned short lB[2][BN * 32];

  int lid = (int)blockIdx.x;
  {
    const int nwg = (int)gridDim.x;
    const int xcd = lid & 7;
    const int q = nwg >> 3, r = nwg & 7;
    const int b2 = (xcd < r) ? xcd * (q + 1) : r * (q + 1) + (xcd - r) * q;
    lid = b2 + (lid >> 3);
  }
  int sidx = 0, kbeg = 0, kend = K;
  if constexpr (EPI == 4) {
    const int nblk = (int)gridDim.x >> 1;
    sidx = lid / nblk;
    lid  = lid % nblk;
    kbeg = sidx * (K >> 1);
    kend = kbeg + (K >> 1);
  }
  const int mtiles = M / BM;
  int m0, n0;
  if constexpr (BM >= 128 && BN == 128) {
    constexpr int GRP = (BM == 256) ? 8 : 16;     // 2048-row stripe (3.1 MB @K=768)
    const int nt = (int)gridDim.x / mtiles;
    const int span = GRP * nt;
    const int g = lid / span, rem = lid % span;
    m0 = (g * GRP + (rem % GRP)) * BM;
    n0 = (rem / GRP) * BN;
  } else {
    m0 = (lid % mtiles) * BM;
    n0 = (lid / mtiles) * BN;
  }

  const int tid = threadIdx.x, wave = tid >> 6, lane = tid & 63;
  const int wr = (wave >> 1) * WM, wc = (wave & 1) * WN;
  const int srow = lane >> 2;
  const int scol = (((lane & 3) ^ ((lane >> 3) & 3))) * 8;  // pre-swizzled source chunk
  const int rdk  = ((lane >> 4) ^ ((lane >> 1) & 3)) * 8;   // swizzled read chunk

  f32x4 acc[MFR][NFR];
#pragma unroll
  for (int i = 0; i < MFR; ++i)
#pragma unroll
    for (int j = 0; j < NFR; ++j) acc[i][j] = (f32x4){0.f, 0.f, 0.f, 0.f};

  const size_t arow0 = (size_t)(m0 + (BM == 256 ? wave * 64 : BM == 128 ? wave * 32 : wave * 16) + srow) * K + scol;
  const size_t brow0 = (size_t)(n0 + (BN == 128 ? wave * 32 : wave * 16) + srow) * K + scol;

  auto stage = [&](int buf, int k0) {
    if constexpr (BM == 256) {
#pragma unroll
      for (int j = 0; j < 4; ++j)
        gld16(A + arow0 + (size_t)(j * 16) * K + k0, lA[buf] + (wave * 4 + j) * 512);
    } else if constexpr (BM == 128) {
      gld16(A + arow0 + k0,                  lA[buf] + (wave * 2 + 0) * 512);
      gld16(A + arow0 + (size_t)16 * K + k0, lA[buf] + (wave * 2 + 1) * 512);
    } else {
      gld16(A + arow0 + k0, lA[buf] + wave * 512);
    }
    if constexpr (BN == 128) {
      gld16(B + brow0 + k0,                  lB[buf] + (wave * 2 + 0) * 512);
      gld16(B + brow0 + (size_t)16 * K + k0, lB[buf] + (wave * 2 + 1) * 512);
    } else {
      gld16(B + brow0 + k0, lB[buf] + wave * 512);
    }
  };

  stage(0, kbeg);
  stage(1, kbeg + 32);
  int cur = 0;
  for (int k0 = kbeg; k0 < kend; k0 += 32) {
    // oldest stage (buffer cur, tile k0) complete; newer stage stays in flight
    asm volatile("s_waitcnt vmcnt(%0)" :: "i"(LPS) : "memory");
    __builtin_amdgcn_s_barrier();
    bf16x8 af[MFR], bfr[NFR];
#pragma unroll
    for (int mi = 0; mi < MFR; ++mi) {
      const int ra = wr + mi * 16 + (lane & 15);
      af[mi] = *(const bf16x8*)&lA[cur][ra * 32 + rdk];
    }
#pragma unroll
    for (int ni = 0; ni < NFR; ++ni) {
      const int rb = wc + ni * 16 + (lane & 15);
      bfr[ni] = *(const bf16x8*)&lB[cur][rb * 32 + rdk];
    }
    asm volatile("s_waitcnt lgkmcnt(0)" ::: "memory");
    __builtin_amdgcn_sched_barrier(0);
    __builtin_amdgcn_s_barrier();            // all waves done reading `cur`
    if (k0 + 64 < kend) stage(cur, k0 + 64); // overwrite cur with tile k+2 (overlaps MFMA)
    __builtin_amdgcn_sched_barrier(0);       // keep load issue ahead of MFMA cluster
#pragma unroll
    for (int mi = 0; mi < MFR; ++mi)
#pragma unroll
      for (int ni = 0; ni < NFR; ++ni)
        acc[mi][ni] = __builtin_amdgcn_mfma_f32_16x16x32_bf16(af[mi], bfr[ni], acc[mi][ni], 0, 0, 0);
    cur ^= 1;
  }

  const int er = (lane >> 4) * 4, ec = lane & 15;
#pragma unroll
  for (int mi = 0; mi < MFR; ++mi) {
#pragma unroll
    for (int r = 0; r < 4; ++r) {
      const size_t row = (size_t)(m0 + wr + mi * 16 + er + r);
#pragma unroll
      for (int ni = 0; ni < NFR; ++ni) {
        float v = acc[mi][ni][r];
        const int col = n0 + wc + ec + ni * 16;
        if constexpr (EPI == 2) {
          const float o = __shfl_xor(v, 1, 64);
          if ((lane & 1) == 0)
            Cg[row * DFF + (col >> 1)] = f2bf((v / (1.f + expf(-v))) * o);
        } else if constexpr (EPI == 1) {
          C[row * N + col] = v + R[row * N + col];
        } else if constexpr (EPI == 3) {
          stream_store(&C[row * N + col], v);
        } else if constexpr (EPI == 4) {
          C[(size_t)sidx * M * N + row * N + col] = v;
        } else {
          C[row * N + col] = v;
        }
      }
    }
  }
}

// split-K join: out = P[0] + P[1] + R  (float4; TOK*DMODEL elems)
__global__ __launch_bounds__(256) void red_k(const float* __restrict__ P, const float* __restrict__ R,
                                             float* __restrict__ out) {
  const size_t i = ((size_t)blockIdx.x * 256 + threadIdx.x) * 4;
  const float4 a = *(const float4*)(P + i);
  const float4 b = *(const float4*)(P + (size_t)TOK * DMODEL + i);
  const float4 r = *(const float4*)(R + i);
  float4 o;
  o.x = a.x + b.x + r.x;
  o.y = a.y + b.y + r.y;
  o.z = a.z + b.z + r.z;
  o.w = a.w + b.w + r.w;
  *(float4*)(out + i) = o;
}

// ---------------- conversions ----------------
__global__ __launch_bounds__(256) void cvt_k(const float* __restrict__ in, unsigned short* __restrict__ out, long n) {
  const long i = ((long)blockIdx.x * 256 + threadIdx.x) * 4;
  if (i >= n) return;
  const float4 v = *(const float4*)(in + i);
  ushort4 o; o.x = f2bf(v.x); o.y = f2bf(v.y); o.z = f2bf(v.z); o.w = f2bf(v.w);
  *(ushort4*)(out + i) = o;
}

__global__ __launch_bounds__(256) void cvt_inw_k(const float* __restrict__ in, unsigned short* __restrict__ out) {
  const int row = blockIdx.x;
  const int l = row / DIPAD, n = row % DIPAD;
  unsigned short* orow = out + (size_t)row * DMODEL;
  if (n >= DIPROJ) {
    for (int c = threadIdx.x; c < DMODEL; c += 256) orow[c] = 0;
    return;
  }
  const float* irow = in + ((size_t)l * DIPROJ + n) * DMODEL;
  for (int c = threadIdx.x; c < DMODEL; c += 256) orow[c] = f2bf(irow[c]);
}

// w1,w2 [L][DFF][DMODEL] -> interleaved w12 [L][2*DFF][DMODEL]: row 2f = w1[f], 2f+1 = w2[f]
__global__ __launch_bounds__(256) void cvt_w12_k(const float* __restrict__ w1, const float* __restrict__ w2,
                                                 unsigned short* __restrict__ out) {
  const int row = blockIdx.x;
  const int l = row / (2 * DFF), rr = row % (2 * DFF);
  const int f = rr >> 1;
  const float* irow = ((rr & 1) == 0) ? (w1 + ((size_t)l * DFF + f) * DMODEL)
                                      : (w2 + ((size_t)l * DFF + f) * DMODEL);
  unsigned short* orow = out + (size_t)row * DMODEL;
  for (int c = threadIdx.x; c < DMODEL; c += 256) orow[c] = f2bf(irow[c]);
}

// ---------------- elementwise / norms (vectorized, G13) ----------------
__global__ __launch_bounds__(192) void embed_k(const int* __restrict__ ids, const float* __restrict__ emb, float* __restrict__ h) {
  const int t = blockIdx.x;
  const float4 v = *(const float4*)(emb + (size_t)ids[t] * DMODEL + threadIdx.x * 4);
  *(float4*)(h + (size_t)t * DMODEL + threadIdx.x * 4) = v;
}

__global__ __launch_bounds__(192) void ln_k(const float* __restrict__ x, const float* __restrict__ w, const float* __restrict__ b,
                                            unsigned short* __restrict__ out) {
  const int t = blockIdx.x, c4 = threadIdx.x * 4;
  const float4 v = *(const float4*)(x + (size_t)t * DMODEL + c4);
  float s = v.x + v.y + v.z + v.w;
  float ss = v.x * v.x + v.y * v.y + v.z * v.z + v.w * v.w;
  red2t<3>(s, ss);
  const float mu = s * (1.f / DMODEL);
  const float inv = rsqrtf(ss * (1.f / DMODEL) - mu * mu + 1e-5f);
  const float4 wv = *(const float4*)(w + c4);
  const float4 bv = *(const float4*)(b + c4);
  ushort4 o;
  o.x = f2bf((v.x - mu) * inv * wv.x + bv.x);
  o.y = f2bf((v.y - mu) * inv * wv.y + bv.y);
  o.z = f2bf((v.z - mu) * inv * wv.z + bv.z);
  o.w = f2bf((v.w - mu) * inv * wv.w + bv.w);
  *(ushort4*)(out + (size_t)t * DMODEL + c4) = o;
}

// conv + SiLU, sliding-window: CTS=8 timesteps/block, register window
// (read amp 1.4x vs old 4x). Skipped taps = fmaf(w,0,acc) -> bit-identical.
__global__ __launch_bounds__(448) void conv_k(const float* __restrict__ zx, const float* __restrict__ cw, const float* __restrict__ cb,
                                              const float* __restrict__ dt_bias, const float* __restrict__ A_log,
                                              float* __restrict__ xs, float* __restrict__ Bm, float* __restrict__ Cm,
                                              float* __restrict__ dtv, float* __restrict__ dAv) {
  const int t0g = blockIdx.x * CTS;
  const int b = t0g >> 11, l0 = t0g & (SEQL - 1);
  const int c4 = threadIdx.x * 4;
  const float4 w0  = *(const float4*)(cw + c4 * 4);
  const float4 w1v = *(const float4*)(cw + c4 * 4 + 4);
  const float4 w2v = *(const float4*)(cw + c4 * 4 + 8);
  const float4 w3v = *(const float4*)(cw + c4 * 4 + 12);
  const float4 bias = *(const float4*)(cb + c4);
  float4 win[3];
#pragma unroll
  for (int j = 0; j < 3; ++j) {
    const int ll = l0 - 3 + j;
    win[j] = (ll >= 0) ? *(const float4*)(zx + (size_t)(b * SEQL + ll) * DIPAD + DINNER + c4)
                       : (float4){0.f, 0.f, 0.f, 0.f};
  }
#pragma unroll
  for (int i = 0; i < CTS; ++i) {
    const int t = t0g + i;
    const float4 cur4 = *(const float4*)(zx + (size_t)t * DIPAD + DINNER + c4);
    float4 a = bias;
    a.x = fmaf(w0.x,  win[0].x, a.x); a.y = fmaf(w1v.x, win[0].y, a.y);
    a.z = fmaf(w2v.x, win[0].z, a.z); a.w = fmaf(w3v.x, win[0].w, a.w);
    a.x = fmaf(w0.y,  win[1].x, a.x); a.y = fmaf(w1v.y, win[1].y, a.y);
    a.z = fmaf(w2v.y, win[1].z, a.z); a.w = fmaf(w3v.y, win[1].w, a.w);
    a.x = fmaf(w0.z,  win[2].x, a.x); a.y = fmaf(w1v.z, win[2].y, a.y);
    a.z = fmaf(w2v.z, win[2].z, a.z); a.w = fmaf(w3v.z, win[2].w, a.w);
    a.x = fmaf(w0.w,  cur4.x, a.x);   a.y = fmaf(w1v.w, cur4.y, a.y);
    a.z = fmaf(w2v.w, cur4.z, a.z);   a.w = fmaf(w3v.w, cur4.w, a.w);
    a.x = a.x / (1.f + expf(-a.x));
    a.y = a.y / (1.f + expf(-a.y));
    a.z = a.z / (1.f + expf(-a.z));
    a.w = a.w / (1.f + expf(-a.w));
    if (threadIdx.x < 384)      *(float4*)(xs + (size_t)t * DINNER + c4) = a;
    else if (threadIdx.x < 416) *(float4*)(Bm + (size_t)t * DSTATE + (c4 - DINNER)) = a;
    else                        *(float4*)(Cm + (size_t)t * DSTATE + (c4 - DINNER - DSTATE)) = a;
    win[0] = win[1]; win[1] = win[2]; win[2] = cur4;
  }
  if (threadIdx.x < NHEADS) {
    const int hh = threadIdx.x;
    const float eA = expf(A_log[hh]);
    const float db = dt_bias[hh];
#pragma unroll
    for (int i = 0; i < CTS; ++i) {
      const int t = t0g + i;
      const float xv = zx[(size_t)t * DIPAD + DINNER + CONVD + hh] + db;
      const float dt = (xv > 20.f) ? xv : log1pf(expf(xv));
      dtv[t * NHEADS + hh] = dt;
      dAv[t * NHEADS + hh] = expf(-dt * eA);
    }
  }
}

// ---------------- chunked SSM scan ----------------
// scan1: B/C LDS-staged in 16-step double-buffered chunks; xp prefetched to regs;
// counted vmcnt (never 0 in-loop). Split-n layout: LDS reads 2-way = free.
__global__ __launch_bounds__(256) void scan1_k(const float* __restrict__ xs, const float* __restrict__ Bm, const float* __restrict__ Cm,
                                               const float* __restrict__ dtv, const float* __restrict__ dAv,
                                               const float* __restrict__ Dp, float* __restrict__ y,
                                               float* __restrict__ Sloc, float* __restrict__ cumv) {
  __shared__ float lB[2][16][128];
  __shared__ float lC[2][16][128];
  __shared__ float sdA[2][16], sdt[2][16];
  const int pg = blockIdx.x, hh = blockIdx.y, z = blockIdx.z;
  const int b = z >> 4, c = z & (NCHUNK - 1);
  const int pl = threadIdx.x >> 4, ln = threadIdx.x & 15;
  const int p = pg * 16 + pl;
  const int wv = threadIdx.x >> 6, lane = threadIdx.x & 63;
  const float Dph = Dp[hh];
  const int bT = b * SEQL + c * CHUNKL;

  auto stage = [&](int buf, int t0) {
#pragma unroll
    for (int j = 0; j < 2; ++j) {
      const int pr = wv + 4 * j;                 // 0..7 row-pairs
      const int row = 2 * pr + (lane >> 5);      // 0..15
      gld16(Bm + (size_t)(t0 + row) * DSTATE + (lane & 31) * 4, &lB[buf][2 * pr][0]);
      gld16(Cm + (size_t)(t0 + row) * DSTATE + (lane & 31) * 4, &lC[buf][2 * pr][0]);
    }
    if (threadIdx.x < 16)      sdA[buf][threadIdx.x]      = dAv[(t0 + threadIdx.x) * NHEADS + hh];
    else if (threadIdx.x < 32) sdt[buf][threadIdx.x - 16] = dtv[(t0 + threadIdx.x - 16) * NHEADS + hh];
  };

  float s0 = 0, s1 = 0, s2 = 0, s3 = 0, s4 = 0, s5 = 0, s6 = 0, s7 = 0;
  float r = 1.f;
  int cur = 0;
  stage(0, bT);
  for (int cc = 0; cc < CHUNKL; cc += 16) {
    const int t0 = bT + cc;
    __builtin_amdgcn_s_barrier();   // all waves done reading the buffer we overwrite next
    float xq[16];
#pragma unroll
    for (int i = 0; i < 16; ++i) xq[i] = xs[(size_t)(t0 + i) * DINNER + hh * HEADD + p];
    if (cc + 16 < CHUNKL) stage(cur ^ 1, t0 + 16);
    asm volatile("s_waitcnt vmcnt(4) lgkmcnt(0)" ::: "memory");  // cur buffer + xq landed; next stage in flight
    __builtin_amdgcn_s_barrier();
#pragma unroll
    for (int i = 0; i < 16; ++i) {
      const float dAt = sdA[cur][i], dtt = sdt[cur][i];
      const float xdt = xq[i] * dtt;
      const float4 B0 = *(const float4*)&lB[cur][i][ln * 4];
      const float4 B1 = *(const float4*)&lB[cur][i][64 + ln * 4];
      const float4 C0 = *(const float4*)&lC[cur][i][ln * 4];
      const float4 C1 = *(const float4*)&lC[cur][i][64 + ln * 4];
      float yp;
      s0 = fmaf(s0, dAt, B0.x * xdt); yp = s0 * C0.x;
      s1 = fmaf(s1, dAt, B0.y * xdt); yp = fmaf(s1, C0.y, yp);
      s2 = fmaf(s2, dAt, B0.z * xdt); yp = fmaf(s2, C0.z, yp);
      s3 = fmaf(s3, dAt, B0.w * xdt); yp = fmaf(s3, C0.w, yp);
      s4 = fmaf(s4, dAt, B1.x * xdt); yp = fmaf(s4, C1.x, yp);
      s5 = fmaf(s5, dAt, B1.y * xdt); yp = fmaf(s5, C1.y, yp);
      s6 = fmaf(s6, dAt, B1.z * xdt); yp = fmaf(s6, C1.z, yp);
      s7 = fmaf(s7, dAt, B1.w * xdt); yp = fmaf(s7, C1.w, yp);
#pragma unroll
      for (int o = 1; o < 16; o <<= 1) yp += __shfl_xor(yp, o, 64);
      if (ln == 0) y[(size_t)(t0 + i) * DINNER + hh * HEADD + p] = fmaf(Dph, xq[i], yp);
      r *= dAt;
      if (threadIdx.x == 0) cumv[(size_t)(b * NHEADS + hh) * SEQL + (c * CHUNKL + cc + i)] = r;
    }
    cur ^= 1;
  }
  float* sp = Sloc + (((size_t)(b * NHEADS + hh) * NCHUNK + c) * HEADD + p) * DSTATE;
  *(float4*)(sp + ln * 4)      = (float4){s0, s1, s2, s3};
  *(float4*)(sp + 64 + ln * 4) = (float4){s4, s5, s6, s7};
}

// scan3 (scan2 fused): each block recomputes S_in[c] from Sloc slots 0..c-1 with the
// SAME fold order the old scan2 used (acc = P_j*acc + Sloc[j-1]) -> bit-identical.
// C LDS-staged (double-buffered 16-step chunks), y prefetched to regs.
__global__ __launch_bounds__(256) void scan3_k(const float* __restrict__ Cm, const float* __restrict__ cumv,
                                               const float* __restrict__ Sloc, float* __restrict__ y) {
  __shared__ float lC[2][16][128];
  __shared__ float sCum[2][16];
  const int pg = blockIdx.x, hh = blockIdx.y, z = blockIdx.z;
  const int b = z / (NCHUNK - 1), c = z % (NCHUNK - 1) + 1;
  const int pl = threadIdx.x >> 4, ln = threadIdx.x & 15;
  const int p = pg * 16 + pl;
  const int wv = threadIdx.x >> 6, lane = threadIdx.x & 63;
  const int bT = b * SEQL + c * CHUNKL;

  // inline inter-chunk combine (was scan2_k)
  float4 sA = (float4){0.f, 0.f, 0.f, 0.f}, sB = (float4){0.f, 0.f, 0.f, 0.f};
  {
    const float* spb = Sloc + ((size_t)(b * NHEADS + hh) * NCHUNK) * (HEADD * DSTATE) + (size_t)p * DSTATE;
    for (int j = 1; j <= c; ++j) {
      const float Pj = cumv[(size_t)(b * NHEADS + hh) * SEQL + j * CHUNKL - 1];
      const float* sj = spb + (size_t)(j - 1) * (HEADD * DSTATE);
      const float4 v0 = *(const float4*)(sj + ln * 4);
      const float4 v1 = *(const float4*)(sj + 64 + ln * 4);
      sA.x = fmaf(Pj, sA.x, v0.x); sA.y = fmaf(Pj, sA.y, v0.y);
      sA.z = fmaf(Pj, sA.z, v0.z); sA.w = fmaf(Pj, sA.w, v0.w);
      sB.x = fmaf(Pj, sB.x, v1.x); sB.y = fmaf(Pj, sB.y, v1.y);
      sB.z = fmaf(Pj, sB.z, v1.z); sB.w = fmaf(Pj, sB.w, v1.w);
    }
  }

  auto stage = [&](int buf, int t0) {
#pragma unroll
    for (int j = 0; j < 2; ++j) {
      const int pr = wv + 4 * j;
      const int row = 2 * pr + (lane >> 5);
      gld16(Cm + (size_t)(t0 + row) * DSTATE + (lane & 31) * 4, &lC[buf][2 * pr][0]);
    }
    if (threadIdx.x < 16)
      sCum[buf][threadIdx.x] = cumv[(size_t)(b * NHEADS + hh) * SEQL + (t0 - b * SEQL) + threadIdx.x];
  };

  int cur = 0;
  stage(0, bT);
  for (int cc = 0; cc < CHUNKL; cc += 16) {
    const int t0 = bT + cc;
    __builtin_amdgcn_s_barrier();
    float yq[16];
#pragma unroll
    for (int i = 0; i < 16; ++i) yq[i] = y[(size_t)(t0 + i) * DINNER + hh * HEADD + p];
    if (cc + 16 < CHUNKL) stage(cur ^ 1, t0 + 16);
    asm volatile("s_waitcnt vmcnt(2) lgkmcnt(0)" ::: "memory");
    __builtin_amdgcn_s_barrier();
#pragma unroll
    for (int i = 0; i < 16; ++i) {
      const float4 C0 = *(const float4*)&lC[cur][i][ln * 4];
      const float4 C1 = *(const float4*)&lC[cur][i][64 + ln * 4];
      float yp = sA.x * C0.x;
      yp = fmaf(sA.y, C0.y, yp);
      yp = fmaf(sA.z, C0.z, yp);
      yp = fmaf(sA.w, C0.w, yp);
      yp = fmaf(sB.x, C1.x, yp);
      yp = fmaf(sB.y, C1.y, yp);
      yp = fmaf(sB.z, C1.z, yp);
      yp = fmaf(sB.w, C1.w, yp);
#pragma unroll
      for (int o = 1; o < 16; o <<= 1) yp += __shfl_xor(yp, o, 64);
      if (ln == 0) y[(size_t)(t0 + i) * DINNER + hh * HEADD + p] = fmaf(sCum[cur][i], yp, yq[i]);
    }
    cur ^= 1;
  }
}

__global__ __launch_bounds__(384) void grms_k(const float* __restrict__ y, const float* __restrict__ zx,
                                              const float* __restrict__ rw, unsigned short* __restrict__ out) {
  const int t = blockIdx.x, c4 = threadIdx.x * 4;
  const float4 yv = *(const float4*)(y + (size_t)t * DINNER + c4);
  const float4 zv = *(const float4*)(zx + (size_t)t * DIPAD + c4);
  float4 g;
  g.x = yv.x * (zv.x / (1.f + expf(-zv.x)));
  g.y = yv.y * (zv.y / (1.f + expf(-zv.y)));
  g.z = yv.z * (zv.z / (1.f + expf(-zv.z)));
  g.w = yv.w * (zv.w / (1.f + expf(-zv.w)));
  float ss = g.x * g.x + g.y * g.y + g.z * g.z + g.w * g.w;
  ss = red1t<6>(ss);
  const float inv = rsqrtf(ss * (1.f / DINNER) + 1e-5f);
  const float4 rv = *(const float4*)(rw + c4);
  ushort4 o;
  o.x = f2bf(g.x * inv * rv.x);
  o.y = f2bf(g.y * inv * rv.y);
  o.z = f2bf(g.z * inv * rv.z);
  o.w = f2bf(g.w * inv * rv.w);
  *(ushort4*)(out + (size_t)t * DINNER + c4) = o;
}

// ---------------- host orchestration ----------------
extern "C" void kernel_launch(void* const* d_in, const int* in_sizes, int n_in,
                              void* d_out, int out_size, void* d_ws, size_t ws_size,
                              hipStream_t stream) {
  const int*   ids      = (const int*)  d_in[0];
  const float* emb      = (const float*)d_in[1];
  const float* ln_w     = (const float*)d_in[2];
  const float* ln_b     = (const float*)d_in[3];
  const float* in_w     = (const float*)d_in[4];
  const float* conv_w   = (const float*)d_in[5];
  const float* conv_b   = (const float*)d_in[6];
  const float* dt_bias  = (const float*)d_in[7];
  const float* A_log    = (const float*)d_in[8];
  const float* Dp       = (const float*)d_in[9];
  const float* rms_w    = (const float*)d_in[10];
  const float* out_w    = (const float*)d_in[11];
  const float* mlp_ln_w = (const float*)d_in[12];
  const float* mlp_ln_b = (const float*)d_in[13];
  const float* w1       = (const float*)d_in[14];
  const float* w2       = (const float*)d_in[15];
  const float* w3       = (const float*)d_in[16];
  const float* normf_w  = (const float*)d_in[17];
  const float* normf_b  = (const float*)d_in[18];
  const float* lm_w     = (const float*)d_in[19];

  char* base = (char*)d_ws;
  size_t off = 0;
  auto alloc = [&](size_t bytes) -> char* {
    char* p = base + off;
    off += (bytes + 255) & ~(size_t)255;
    return p;
  };
  float* h             = (float*)alloc((size_t)TOK * DMODEL * 4);
  unsigned short* xn   = (unsigned short*)alloc((size_t)TOK * DMODEL * 2);
  float* zx            = (float*)alloc((size_t)TOK * DIPAD * 4);
  float* xs            = (float*)alloc((size_t)TOK * DINNER * 4);
  float* Bm            = (float*)alloc((size_t)TOK * DSTATE * 4);
  float* Cm            = (float*)alloc((size_t)TOK * DSTATE * 4);
  float* dtv           = (float*)alloc((size_t)TOK * NHEADS * 4);
  float* dAv           = (float*)alloc((size_t)TOK * NHEADS * 4);
  float* y             = (float*)alloc((size_t)TOK * DINNER * 4);
  unsigned short* ybf  = (unsigned short*)alloc((size_t)TOK * DINNER * 2);
  float* hf            = (float*)alloc((size_t)TOK * DMODEL * 4);
  unsigned short* gbf  = (unsigned short*)alloc((size_t)TOK * DMODEL * 2);
  unsigned short* gate = (unsigned short*)alloc((size_t)TOK * DFF * 2);
  float* Sloc          = (float*)alloc((size_t)2 * NHEADS * NCHUNK * HEADD * DSTATE * 4);
  float* cumv          = (float*)alloc((size_t)2 * NHEADS * SEQL * 4);
  float* Cpart         = (float*)alloc((size_t)2 * TOK * DMODEL * 4);
  unsigned short* inw_bf  = (unsigned short*)alloc((size_t)NLAYER * DIPAD * DMODEL * 2);
  unsigned short* outw_bf = (unsigned short*)alloc((size_t)NLAYER * DMODEL * DINNER * 2);
  unsigned short* w12_bf  = (unsigned short*)alloc((size_t)NLAYER * 2 * DFF * DMODEL * 2);
  unsigned short* w3_bf   = (unsigned short*)alloc((size_t)NLAYER * DMODEL * DFF * 2);
  unsigned short* lm_bf   = (unsigned short*)alloc((size_t)VOCABN * DMODEL * 2);
  if (off > ws_size) return;

  cvt_inw_k<<<NLAYER * DIPAD, 256, 0, stream>>>(in_w, inw_bf);
  cvt_w12_k<<<NLAYER * 2 * DFF, 256, 0, stream>>>(w1, w2, w12_bf);
  {
    const long n1 = (long)NLAYER * DMODEL * DINNER;
    cvt_k<<<(unsigned)((n1 + 1023) / 1024), 256, 0, stream>>>(out_w, outw_bf, n1);
    const long n3 = (long)NLAYER * DMODEL * DFF;
    cvt_k<<<(unsigned)((n3 + 1023) / 1024), 256, 0, stream>>>(w3, w3_bf, n3);
    const long n4 = (long)VOCABN * DMODEL;
    cvt_k<<<(unsigned)((n4 + 1023) / 1024), 256, 0, stream>>>(lm_w, lm_bf, n4);
  }

  embed_k<<<TOK, 192, 0, stream>>>(ids, emb, h);

  for (int l = 0; l < NLAYER; ++l) {
    ln_k<<<TOK, 192, 0, stream>>>(h, ln_w + l * DMODEL, ln_b + l * DMODEL, xn);
    gemm_bt<0, 256, 128><<<(TOK / 256) * (DIPAD / 128), 256, 0, stream>>>(
        xn, inw_bf + (size_t)l * DIPAD * DMODEL, zx, nullptr, nullptr, TOK, DIPAD, DMODEL);
    conv_k<<<TOK / CTS, 448, 0, stream>>>(zx, conv_w + (size_t)l * CONVD * 4, conv_b + (size_t)l * CONVD,
                                          dt_bias + l * NHEADS, A_log + l * NHEADS, xs, Bm, Cm, dtv, dAv);
    scan1_k<<<dim3(4, NHEADS, 2 * NCHUNK), 256, 0, stream>>>(xs, Bm, Cm, dtv, dAv, Dp + l * NHEADS, y, Sloc, cumv);
    scan3_k<<<dim3(4, NHEADS, 2 * (NCHUNK - 1)), 256, 0, stream>>>(Cm, cumv, Sloc, y);
    grms_k<<<TOK, 384, 0, stream>>>(y, zx, rms_w + (size_t)l * DINNER, ybf);
    gemm_bt<4, 128, 64><<<2 * (TOK / 128) * (DMODEL / 64), 256, 0, stream>>>(
        ybf, outw_bf + (size_t)l * DMODEL * DINNER, Cpart, nullptr, nullptr, TOK, DMODEL, DINNER);
    red_k<<<TOK * DMODEL / 1024, 256, 0, stream>>>(Cpart, h, hf);
    ln_k<<<TOK, 192, 0, stream>>>(hf, mlp_ln_w + l * DMODEL, mlp_ln_b + l * DMODEL, gbf);
    gemm_bt<2, 256, 128><<<(TOK / 256) * (2 * DFF / 128), 256, 0, stream>>>(
        gbf, w12_bf + (size_t)l * 2 * DFF * DMODEL, nullptr, gate, nullptr, TOK, 2 * DFF, DMODEL);
    gemm_bt<4, 128, 64><<<2 * (TOK / 128) * (DMODEL / 64), 256, 0, stream>>>(
        gate, w3_bf + (size_t)l * DMODEL * DFF, Cpart, nullptr, nullptr, TOK, DMODEL, DFF);
    red_k<<<TOK * DMODEL / 1024, 256, 0, stream>>>(Cpart, hf, h);
  }

  ln_k<<<TOK, 192, 0, stream>>>(h, normf_w, normf_b, xn);
  gemm_bt<3, 256, 128><<<(TOK / 256) * (VOCABN / 128), 256, 0, stream>>>(
      xn, lm_bf, (float*)d_out, nullptr, nullptr, TOK, VOCABN, DMODEL);
}

// Round 15
// 5687.847 us; speedup vs baseline: 1.0270x; 1.0156x over previous
//
#include <hip/hip_runtime.h>
#include <cstdint>
#include <cstddef>

#define TOK    4096
#define SEQL   2048
#define DMODEL 768
#define NLAYER 12
#define DSTATE 128
#define HEADD  64
#define DINNER 1536
#define NHEADS 24
#define CONVD  1792
#define DIPROJ 3352
#define DIPAD  3456
#define DFF    2048
#define VOCABN 32000
#define NCHUNK 16
#define CHUNKL 128
#define CTS    8

typedef __attribute__((ext_vector_type(8))) short bf16x8;
typedef __attribute__((ext_vector_type(4))) float f32x4;

__device__ __forceinline__ unsigned short f2bf(float f) {
  union { float f; unsigned u; } v; v.f = f;
  return (unsigned short)((v.u + 0x7FFFu + ((v.u >> 16) & 1u)) >> 16);
}

__device__ __forceinline__ void gld16(const void* g, void* l) {
  __builtin_amdgcn_global_load_lds(
      (const __attribute__((address_space(1))) unsigned int*)g,
      (__attribute__((address_space(3))) unsigned int*)l, 16, 0, 0);
}

// streaming store: bypass L2/L3 allocation (sc0 sc1 nt) — logits are never re-read
__device__ __forceinline__ void stream_store(float* addr, float v) {
  asm volatile("global_store_dword %0, %1, off sc0 sc1 nt" :: "v"(addr), "v"(v) : "memory");
}

// ---------------- block reductions (template wave count) ----------------
template <int NW>
__device__ __forceinline__ void red2t(float& a, float& b) {
#pragma unroll
  for (int o = 1; o < 64; o <<= 1) { a += __shfl_xor(a, o, 64); b += __shfl_xor(b, o, 64); }
  __shared__ float sa[NW], sb[NW];
  const int w = threadIdx.x >> 6;
  if ((threadIdx.x & 63) == 0) { sa[w] = a; sb[w] = b; }
  __syncthreads();
  a = sa[0]; b = sb[0];
#pragma unroll
  for (int i = 1; i < NW; ++i) { a += sa[i]; b += sb[i]; }
}

template <int NW>
__device__ __forceinline__ float red1t(float a) {
#pragma unroll
  for (int o = 1; o < 64; o <<= 1) a += __shfl_xor(a, o, 64);
  __shared__ float sa[NW];
  const int w = threadIdx.x >> 6;
  if ((threadIdx.x & 63) == 0) sa[w] = a;
  __syncthreads();
  float r = sa[0];
#pragma unroll
  for (int i = 1; i < NW; ++i) r += sa[i];
  return r;
}

// ---------------- GEMM: C[m,n] = sum_k A[m,k]*B[n,k], bf16 in / f32 out ----------------
// EXACT round-12 proven structure (best measured): 2-buffer ring, K-step =
// vmcnt(LPS) -> barrier -> ds_reads -> lgkmcnt(0)+sched_barrier -> barrier ->
// stage(cur,k+2) BEFORE MFMA -> MFMA. (256,2) is load-bearing (r11 spill).
// EPI: 0 = store C; 1 = store C+R; 2 = silu-gate pair -> bf16 Cg (w12 fused);
//      3 = streaming store (LM head); 4 = split-K=2 partial store (out_proj/w3).
template <int EPI, int BM, int BN>
__global__ __launch_bounds__(256, 2) void gemm_bt(
    const unsigned short* __restrict__ A, const unsigned short* __restrict__ B,
    float* __restrict__ C, unsigned short* __restrict__ Cg,
    const float* __restrict__ R, int M, int N, int K) {
  constexpr int WM  = BM / 2, WN = BN / 2;
  constexpr int MFR = WM / 16, NFR = WN / 16;
  constexpr int LPS = (BM == 256 ? 4 : BM == 128 ? 2 : 1) + (BN == 128 ? 2 : 1);
  __shared__ unsigned short lA[2][BM * 32];
  __shared__ unsigned short lB[2][BN * 32];

  int lid = (int)blockIdx.x;
  {
    const int nwg = (int)gridDim.x;
    const int xcd = lid & 7;
    const int q = nwg >> 3, r = nwg & 7;
    const int b2 = (xcd < r) ? xcd * (q + 1) : r * (q + 1) + (xcd - r) * q;
    lid = b2 + (lid >> 3);
  }
  int sidx = 0, kbeg = 0, kend = K;
  if constexpr (EPI == 4) {
    const int nblk = (int)gridDim.x >> 1;
    sidx = lid / nblk;
    lid  = lid % nblk;
    kbeg = sidx * (K >> 1);
    kend = kbeg + (K >> 1);
  }
  const int mtiles = M / BM;
  int m0, n0;
  if constexpr (BM >= 128 && BN == 128) {
    constexpr int GRP = (BM == 256) ? 8 : 16;     // 2048-row stripe (3.1 MB @K=768)
    const int nt = (int)gridDim.x / mtiles;
    const int span = GRP * nt;
    const int g = lid / span, rem = lid % span;
    m0 = (g * GRP + (rem % GRP)) * BM;
    n0 = (rem / GRP) * BN;
  } else {
    m0 = (lid % mtiles) * BM;
    n0 = (lid / mtiles) * BN;
  }

  const int tid = threadIdx.x, wave = tid >> 6, lane = tid & 63;
  const int wr = (wave >> 1) * WM, wc = (wave & 1) * WN;
  const int srow = lane >> 2;
  const int scol = (((lane & 3) ^ ((lane >> 3) & 3))) * 8;  // pre-swizzled source chunk
  const int rdk  = ((lane >> 4) ^ ((lane >> 1) & 3)) * 8;   // swizzled read chunk

  f32x4 acc[MFR][NFR];
#pragma unroll
  for (int i = 0; i < MFR; ++i)
#pragma unroll
    for (int j = 0; j < NFR; ++j) acc[i][j] = (f32x4){0.f, 0.f, 0.f, 0.f};

  const size_t arow0 = (size_t)(m0 + (BM == 256 ? wave * 64 : BM == 128 ? wave * 32 : wave * 16) + srow) * K + scol;
  const size_t brow0 = (size_t)(n0 + (BN == 128 ? wave * 32 : wave * 16) + srow) * K + scol;

  auto stage = [&](int buf, int k0) {
    if constexpr (BM == 256) {
#pragma unroll
      for (int j = 0; j < 4; ++j)
        gld16(A + arow0 + (size_t)(j * 16) * K + k0, lA[buf] + (wave * 4 + j) * 512);
    } else if constexpr (BM == 128) {
      gld16(A + arow0 + k0,                  lA[buf] + (wave * 2 + 0) * 512);
      gld16(A + arow0 + (size_t)16 * K + k0, lA[buf] + (wave * 2 + 1) * 512);
    } else {
      gld16(A + arow0 + k0, lA[buf] + wave * 512);
    }
    if constexpr (BN == 128) {
      gld16(B + brow0 + k0,                  lB[buf] + (wave * 2 + 0) * 512);
      gld16(B + brow0 + (size_t)16 * K + k0, lB[buf] + (wave * 2 + 1) * 512);
    } else {
      gld16(B + brow0 + k0, lB[buf] + wave * 512);
    }
  };

  stage(0, kbeg);
  stage(1, kbeg + 32);
  int cur = 0;
  for (int k0 = kbeg; k0 < kend; k0 += 32) {
    // oldest stage (buffer cur, tile k0) complete; newer stage stays in flight
    asm volatile("s_waitcnt vmcnt(%0)" :: "i"(LPS) : "memory");
    __builtin_amdgcn_s_barrier();
    bf16x8 af[MFR], bfr[NFR];
#pragma unroll
    for (int mi = 0; mi < MFR; ++mi) {
      const int ra = wr + mi * 16 + (lane & 15);
      af[mi] = *(const bf16x8*)&lA[cur][ra * 32 + rdk];
    }
#pragma unroll
    for (int ni = 0; ni < NFR; ++ni) {
      const int rb = wc + ni * 16 + (lane & 15);
      bfr[ni] = *(const bf16x8*)&lB[cur][rb * 32 + rdk];
    }
    asm volatile("s_waitcnt lgkmcnt(0)" ::: "memory");
    __builtin_amdgcn_sched_barrier(0);
    __builtin_amdgcn_s_barrier();            // all waves done reading `cur`
    if (k0 + 64 < kend) stage(cur, k0 + 64); // overwrite cur with tile k+2 (overlaps MFMA)
    __builtin_amdgcn_sched_barrier(0);       // keep load issue ahead of MFMA cluster
#pragma unroll
    for (int mi = 0; mi < MFR; ++mi)
#pragma unroll
      for (int ni = 0; ni < NFR; ++ni)
        acc[mi][ni] = __builtin_amdgcn_mfma_f32_16x16x32_bf16(af[mi], bfr[ni], acc[mi][ni], 0, 0, 0);
    cur ^= 1;
  }

  const int er = (lane >> 4) * 4, ec = lane & 15;
#pragma unroll
  for (int mi = 0; mi < MFR; ++mi) {
#pragma unroll
    for (int r = 0; r < 4; ++r) {
      const size_t row = (size_t)(m0 + wr + mi * 16 + er + r);
#pragma unroll
      for (int ni = 0; ni < NFR; ++ni) {
        float v = acc[mi][ni][r];
        const int col = n0 + wc + ec + ni * 16;
        if constexpr (EPI == 2) {
          const float o = __shfl_xor(v, 1, 64);
          if ((lane & 1) == 0)
            Cg[row * DFF + (col >> 1)] = f2bf((v / (1.f + expf(-v))) * o);
        } else if constexpr (EPI == 1) {
          C[row * N + col] = v + R[row * N + col];
        } else if constexpr (EPI == 3) {
          stream_store(&C[row * N + col], v);
        } else if constexpr (EPI == 4) {
          C[(size_t)sidx * M * N + row * N + col] = v;
        } else {
          C[row * N + col] = v;
        }
      }
    }
  }
}

// fused split-K join + LayerNorm: hout = P[0]+P[1]+R (stored, residual stream);
// out_bf = LN(hout)*w+b. Same add order as old red_k then ln_k -> bit-identical.
__global__ __launch_bounds__(192) void redln_k(const float* __restrict__ P, const float* __restrict__ R,
                                               float* __restrict__ hout,
                                               const float* __restrict__ w, const float* __restrict__ b,
                                               unsigned short* __restrict__ out) {
  const int t = blockIdx.x, c4 = threadIdx.x * 4;
  const size_t i = (size_t)t * DMODEL + c4;
  const float4 a = *(const float4*)(P + i);
  const float4 p2 = *(const float4*)(P + (size_t)TOK * DMODEL + i);
  const float4 r = *(const float4*)(R + i);
  float4 v;
  v.x = a.x + p2.x + r.x;
  v.y = a.y + p2.y + r.y;
  v.z = a.z + p2.z + r.z;
  v.w = a.w + p2.w + r.w;
  *(float4*)(hout + i) = v;
  float s = v.x + v.y + v.z + v.w;
  float ss = v.x * v.x + v.y * v.y + v.z * v.z + v.w * v.w;
  red2t<3>(s, ss);
  const float mu = s * (1.f / DMODEL);
  const float inv = rsqrtf(ss * (1.f / DMODEL) - mu * mu + 1e-5f);
  const float4 wv = *(const float4*)(w + c4);
  const float4 bv = *(const float4*)(b + c4);
  ushort4 o;
  o.x = f2bf((v.x - mu) * inv * wv.x + bv.x);
  o.y = f2bf((v.y - mu) * inv * wv.y + bv.y);
  o.z = f2bf((v.z - mu) * inv * wv.z + bv.z);
  o.w = f2bf((v.w - mu) * inv * wv.w + bv.w);
  *(ushort4*)(out + i) = o;
}

// ---------------- conversions ----------------
__global__ __launch_bounds__(256) void cvt_k(const float* __restrict__ in, unsigned short* __restrict__ out, long n) {
  const long i = ((long)blockIdx.x * 256 + threadIdx.x) * 4;
  if (i >= n) return;
  const float4 v = *(const float4*)(in + i);
  ushort4 o; o.x = f2bf(v.x); o.y = f2bf(v.y); o.z = f2bf(v.z); o.w = f2bf(v.w);
  *(ushort4*)(out + i) = o;
}

__global__ __launch_bounds__(256) void cvt_inw_k(const float* __restrict__ in, unsigned short* __restrict__ out) {
  const int row = blockIdx.x;
  const int l = row / DIPAD, n = row % DIPAD;
  unsigned short* orow = out + (size_t)row * DMODEL;
  if (n >= DIPROJ) {
    for (int c = threadIdx.x; c < DMODEL; c += 256) orow[c] = 0;
    return;
  }
  const float* irow = in + ((size_t)l * DIPROJ + n) * DMODEL;
  for (int c = threadIdx.x; c < DMODEL; c += 256) orow[c] = f2bf(irow[c]);
}

// w1,w2 [L][DFF][DMODEL] -> interleaved w12 [L][2*DFF][DMODEL]: row 2f = w1[f], 2f+1 = w2[f]
__global__ __launch_bounds__(256) void cvt_w12_k(const float* __restrict__ w1, const float* __restrict__ w2,
                                                 unsigned short* __restrict__ out) {
  const int row = blockIdx.x;
  const int l = row / (2 * DFF), rr = row % (2 * DFF);
  const int f = rr >> 1;
  const float* irow = ((rr & 1) == 0) ? (w1 + ((size_t)l * DFF + f) * DMODEL)
                                      : (w2 + ((size_t)l * DFF + f) * DMODEL);
  unsigned short* orow = out + (size_t)row * DMODEL;
  for (int c = threadIdx.x; c < DMODEL; c += 256) orow[c] = f2bf(irow[c]);
}

// ---------------- elementwise / norms (vectorized, G13) ----------------
__global__ __launch_bounds__(192) void embed_k(const int* __restrict__ ids, const float* __restrict__ emb, float* __restrict__ h) {
  const int t = blockIdx.x;
  const float4 v = *(const float4*)(emb + (size_t)ids[t] * DMODEL + threadIdx.x * 4);
  *(float4*)(h + (size_t)t * DMODEL + threadIdx.x * 4) = v;
}

__global__ __launch_bounds__(192) void ln_k(const float* __restrict__ x, const float* __restrict__ w, const float* __restrict__ b,
                                            unsigned short* __restrict__ out) {
  const int t = blockIdx.x, c4 = threadIdx.x * 4;
  const float4 v = *(const float4*)(x + (size_t)t * DMODEL + c4);
  float s = v.x + v.y + v.z + v.w;
  float ss = v.x * v.x + v.y * v.y + v.z * v.z + v.w * v.w;
  red2t<3>(s, ss);
  const float mu = s * (1.f / DMODEL);
  const float inv = rsqrtf(ss * (1.f / DMODEL) - mu * mu + 1e-5f);
  const float4 wv = *(const float4*)(w + c4);
  const float4 bv = *(const float4*)(b + c4);
  ushort4 o;
  o.x = f2bf((v.x - mu) * inv * wv.x + bv.x);
  o.y = f2bf((v.y - mu) * inv * wv.y + bv.y);
  o.z = f2bf((v.z - mu) * inv * wv.z + bv.z);
  o.w = f2bf((v.w - mu) * inv * wv.w + bv.w);
  *(ushort4*)(out + (size_t)t * DMODEL + c4) = o;
}

// conv + SiLU, sliding-window: CTS=8 timesteps/block, register window
// (read amp 1.4x vs old 4x). Skipped taps = fmaf(w,0,acc) -> bit-identical.
__global__ __launch_bounds__(448) void conv_k(const float* __restrict__ zx, const float* __restrict__ cw, const float* __restrict__ cb,
                                              const float* __restrict__ dt_bias, const float* __restrict__ A_log,
                                              float* __restrict__ xs, float* __restrict__ Bm, float* __restrict__ Cm,
                                              float* __restrict__ dtv, float* __restrict__ dAv) {
  const int t0g = blockIdx.x * CTS;
  const int b = t0g >> 11, l0 = t0g & (SEQL - 1);
  const int c4 = threadIdx.x * 4;
  const float4 w0  = *(const float4*)(cw + c4 * 4);
  const float4 w1v = *(const float4*)(cw + c4 * 4 + 4);
  const float4 w2v = *(const float4*)(cw + c4 * 4 + 8);
  const float4 w3v = *(const float4*)(cw + c4 * 4 + 12);
  const float4 bias = *(const float4*)(cb + c4);
  float4 win[3];
#pragma unroll
  for (int j = 0; j < 3; ++j) {
    const int ll = l0 - 3 + j;
    win[j] = (ll >= 0) ? *(const float4*)(zx + (size_t)(b * SEQL + ll) * DIPAD + DINNER + c4)
                       : (float4){0.f, 0.f, 0.f, 0.f};
  }
#pragma unroll
  for (int i = 0; i < CTS; ++i) {
    const int t = t0g + i;
    const float4 cur4 = *(const float4*)(zx + (size_t)t * DIPAD + DINNER + c4);
    float4 a = bias;
    a.x = fmaf(w0.x,  win[0].x, a.x); a.y = fmaf(w1v.x, win[0].y, a.y);
    a.z = fmaf(w2v.x, win[0].z, a.z); a.w = fmaf(w3v.x, win[0].w, a.w);
    a.x = fmaf(w0.y,  win[1].x, a.x); a.y = fmaf(w1v.y, win[1].y, a.y);
    a.z = fmaf(w2v.y, win[1].z, a.z); a.w = fmaf(w3v.y, win[1].w, a.w);
    a.x = fmaf(w0.z,  win[2].x, a.x); a.y = fmaf(w1v.z, win[2].y, a.y);
    a.z = fmaf(w2v.z, win[2].z, a.z); a.w = fmaf(w3v.z, win[2].w, a.w);
    a.x = fmaf(w0.w,  cur4.x, a.x);   a.y = fmaf(w1v.w, cur4.y, a.y);
    a.z = fmaf(w2v.w, cur4.z, a.z);   a.w = fmaf(w3v.w, cur4.w, a.w);
    a.x = a.x / (1.f + expf(-a.x));
    a.y = a.y / (1.f + expf(-a.y));
    a.z = a.z / (1.f + expf(-a.z));
    a.w = a.w / (1.f + expf(-a.w));
    if (threadIdx.x < 384)      *(float4*)(xs + (size_t)t * DINNER + c4) = a;
    else if (threadIdx.x < 416) *(float4*)(Bm + (size_t)t * DSTATE + (c4 - DINNER)) = a;
    else                        *(float4*)(Cm + (size_t)t * DSTATE + (c4 - DINNER - DSTATE)) = a;
    win[0] = win[1]; win[1] = win[2]; win[2] = cur4;
  }
  if (threadIdx.x < NHEADS) {
    const int hh = threadIdx.x;
    const float eA = expf(A_log[hh]);
    const float db = dt_bias[hh];
#pragma unroll
    for (int i = 0; i < CTS; ++i) {
      const int t = t0g + i;
      const float xv = zx[(size_t)t * DIPAD + DINNER + CONVD + hh] + db;
      const float dt = (xv > 20.f) ? xv : log1pf(expf(xv));
      dtv[t * NHEADS + hh] = dt;
      dAv[t * NHEADS + hh] = expf(-dt * eA);
    }
  }
}

// ---------------- chunked SSM scan ----------------
__global__ __launch_bounds__(256) void scan1_k(const float* __restrict__ xs, const float* __restrict__ Bm, const float* __restrict__ Cm,
                                               const float* __restrict__ dtv, const float* __restrict__ dAv,
                                               const float* __restrict__ Dp, float* __restrict__ y,
                                               float* __restrict__ Sloc, float* __restrict__ cumv) {
  __shared__ float lB[2][16][128];
  __shared__ float lC[2][16][128];
  __shared__ float sdA[2][16], sdt[2][16];
  const int pg = blockIdx.x, hh = blockIdx.y, z = blockIdx.z;
  const int b = z >> 4, c = z & (NCHUNK - 1);
  const int pl = threadIdx.x >> 4, ln = threadIdx.x & 15;
  const int p = pg * 16 + pl;
  const int wv = threadIdx.x >> 6, lane = threadIdx.x & 63;
  const float Dph = Dp[hh];
  const int bT = b * SEQL + c * CHUNKL;

  auto stage = [&](int buf, int t0) {
#pragma unroll
    for (int j = 0; j < 2; ++j) {
      const int pr = wv + 4 * j;                 // 0..7 row-pairs
      const int row = 2 * pr + (lane >> 5);      // 0..15
      gld16(Bm + (size_t)(t0 + row) * DSTATE + (lane & 31) * 4, &lB[buf][2 * pr][0]);
      gld16(Cm + (size_t)(t0 + row) * DSTATE + (lane & 31) * 4, &lC[buf][2 * pr][0]);
    }
    if (threadIdx.x < 16)      sdA[buf][threadIdx.x]      = dAv[(t0 + threadIdx.x) * NHEADS + hh];
    else if (threadIdx.x < 32) sdt[buf][threadIdx.x - 16] = dtv[(t0 + threadIdx.x - 16) * NHEADS + hh];
  };

  float s0 = 0, s1 = 0, s2 = 0, s3 = 0, s4 = 0, s5 = 0, s6 = 0, s7 = 0;
  float r = 1.f;
  int cur = 0;
  stage(0, bT);
  for (int cc = 0; cc < CHUNKL; cc += 16) {
    const int t0 = bT + cc;
    __builtin_amdgcn_s_barrier();   // all waves done reading the buffer we overwrite next
    float xq[16];
#pragma unroll
    for (int i = 0; i < 16; ++i) xq[i] = xs[(size_t)(t0 + i) * DINNER + hh * HEADD + p];
    if (cc + 16 < CHUNKL) stage(cur ^ 1, t0 + 16);
    asm volatile("s_waitcnt vmcnt(4) lgkmcnt(0)" ::: "memory");  // cur buffer + xq landed; next stage in flight
    __builtin_amdgcn_s_barrier();
#pragma unroll
    for (int i = 0; i < 16; ++i) {
      const float dAt = sdA[cur][i], dtt = sdt[cur][i];
      const float xdt = xq[i] * dtt;
      const float4 B0 = *(const float4*)&lB[cur][i][ln * 4];
      const float4 B1 = *(const float4*)&lB[cur][i][64 + ln * 4];
      const float4 C0 = *(const float4*)&lC[cur][i][ln * 4];
      const float4 C1 = *(const float4*)&lC[cur][i][64 + ln * 4];
      float yp;
      s0 = fmaf(s0, dAt, B0.x * xdt); yp = s0 * C0.x;
      s1 = fmaf(s1, dAt, B0.y * xdt); yp = fmaf(s1, C0.y, yp);
      s2 = fmaf(s2, dAt, B0.z * xdt); yp = fmaf(s2, C0.z, yp);
      s3 = fmaf(s3, dAt, B0.w * xdt); yp = fmaf(s3, C0.w, yp);
      s4 = fmaf(s4, dAt, B1.x * xdt); yp = fmaf(s4, C1.x, yp);
      s5 = fmaf(s5, dAt, B1.y * xdt); yp = fmaf(s5, C1.y, yp);
      s6 = fmaf(s6, dAt, B1.z * xdt); yp = fmaf(s6, C1.z, yp);
      s7 = fmaf(s7, dAt, B1.w * xdt); yp = fmaf(s7, C1.w, yp);
#pragma unroll
      for (int o = 1; o < 16; o <<= 1) yp += __shfl_xor(yp, o, 64);
      if (ln == 0) y[(size_t)(t0 + i) * DINNER + hh * HEADD + p] = fmaf(Dph, xq[i], yp);
      r *= dAt;
      if (threadIdx.x == 0) cumv[(size_t)(b * NHEADS + hh) * SEQL + (c * CHUNKL + cc + i)] = r;
    }
    cur ^= 1;
  }
  float* sp = Sloc + (((size_t)(b * NHEADS + hh) * NCHUNK + c) * HEADD + p) * DSTATE;
  *(float4*)(sp + ln * 4)      = (float4){s0, s1, s2, s3};
  *(float4*)(sp + 64 + ln * 4) = (float4){s4, s5, s6, s7};
}

// scan3 (scan2 fused): recompute S_in[c] with the same fold order -> bit-identical.
__global__ __launch_bounds__(256) void scan3_k(const float* __restrict__ Cm, const float* __restrict__ cumv,
                                               const float* __restrict__ Sloc, float* __restrict__ y) {
  __shared__ float lC[2][16][128];
  __shared__ float sCum[2][16];
  const int pg = blockIdx.x, hh = blockIdx.y, z = blockIdx.z;
  const int b = z / (NCHUNK - 1), c = z % (NCHUNK - 1) + 1;
  const int pl = threadIdx.x >> 4, ln = threadIdx.x & 15;
  const int p = pg * 16 + pl;
  const int wv = threadIdx.x >> 6, lane = threadIdx.x & 63;
  const int bT = b * SEQL + c * CHUNKL;

  float4 sA = (float4){0.f, 0.f, 0.f, 0.f}, sB = (float4){0.f, 0.f, 0.f, 0.f};
  {
    const float* spb = Sloc + ((size_t)(b * NHEADS + hh) * NCHUNK) * (HEADD * DSTATE) + (size_t)p * DSTATE;
    for (int j = 1; j <= c; ++j) {
      const float Pj = cumv[(size_t)(b * NHEADS + hh) * SEQL + j * CHUNKL - 1];
      const float* sj = spb + (size_t)(j - 1) * (HEADD * DSTATE);
      const float4 v0 = *(const float4*)(sj + ln * 4);
      const float4 v1 = *(const float4*)(sj + 64 + ln * 4);
      sA.x = fmaf(Pj, sA.x, v0.x); sA.y = fmaf(Pj, sA.y, v0.y);
      sA.z = fmaf(Pj, sA.z, v0.z); sA.w = fmaf(Pj, sA.w, v0.w);
      sB.x = fmaf(Pj, sB.x, v1.x); sB.y = fmaf(Pj, sB.y, v1.y);
      sB.z = fmaf(Pj, sB.z, v1.z); sB.w = fmaf(Pj, sB.w, v1.w);
    }
  }

  auto stage = [&](int buf, int t0) {
#pragma unroll
    for (int j = 0; j < 2; ++j) {
      const int pr = wv + 4 * j;
      const int row = 2 * pr + (lane >> 5);
      gld16(Cm + (size_t)(t0 + row) * DSTATE + (lane & 31) * 4, &lC[buf][2 * pr][0]);
    }
    if (threadIdx.x < 16)
      sCum[buf][threadIdx.x] = cumv[(size_t)(b * NHEADS + hh) * SEQL + (t0 - b * SEQL) + threadIdx.x];
  };

  int cur = 0;
  stage(0, bT);
  for (int cc = 0; cc < CHUNKL; cc += 16) {
    const int t0 = bT + cc;
    __builtin_amdgcn_s_barrier();
    float yq[16];
#pragma unroll
    for (int i = 0; i < 16; ++i) yq[i] = y[(size_t)(t0 + i) * DINNER + hh * HEADD + p];
    if (cc + 16 < CHUNKL) stage(cur ^ 1, t0 + 16);
    asm volatile("s_waitcnt vmcnt(2) lgkmcnt(0)" ::: "memory");
    __builtin_amdgcn_s_barrier();
#pragma unroll
    for (int i = 0; i < 16; ++i) {
      const float4 C0 = *(const float4*)&lC[cur][i][ln * 4];
      const float4 C1 = *(const float4*)&lC[cur][i][64 + ln * 4];
      float yp = sA.x * C0.x;
      yp = fmaf(sA.y, C0.y, yp);
      yp = fmaf(sA.z, C0.z, yp);
      yp = fmaf(sA.w, C0.w, yp);
      yp = fmaf(sB.x, C1.x, yp);
      yp = fmaf(sB.y, C1.y, yp);
      yp = fmaf(sB.z, C1.z, yp);
      yp = fmaf(sB.w, C1.w, yp);
#pragma unroll
      for (int o = 1; o < 16; o <<= 1) yp += __shfl_xor(yp, o, 64);
      if (ln == 0) y[(size_t)(t0 + i) * DINNER + hh * HEADD + p] = fmaf(sCum[cur][i], yp, yq[i]);
    }
    cur ^= 1;
  }
}

__global__ __launch_bounds__(384) void grms_k(const float* __restrict__ y, const float* __restrict__ zx,
                                              const float* __restrict__ rw, unsigned short* __restrict__ out) {
  const int t = blockIdx.x, c4 = threadIdx.x * 4;
  const float4 yv = *(const float4*)(y + (size_t)t * DINNER + c4);
  const float4 zv = *(const float4*)(zx + (size_t)t * DIPAD + c4);
  float4 g;
  g.x = yv.x * (zv.x / (1.f + expf(-zv.x)));
  g.y = yv.y * (zv.y / (1.f + expf(-zv.y)));
  g.z = yv.z * (zv.z / (1.f + expf(-zv.z)));
  g.w = yv.w * (zv.w / (1.f + expf(-zv.w)));
  float ss = g.x * g.x + g.y * g.y + g.z * g.z + g.w * g.w;
  ss = red1t<6>(ss);
  const float inv = rsqrtf(ss * (1.f / DINNER) + 1e-5f);
  const float4 rv = *(const float4*)(rw + c4);
  ushort4 o;
  o.x = f2bf(g.x * inv * rv.x);
  o.y = f2bf(g.y * inv * rv.y);
  o.z = f2bf(g.z * inv * rv.z);
  o.w = f2bf(g.w * inv * rv.w);
  *(ushort4*)(out + (size_t)t * DINNER + c4) = o;
}

// ---------------- host orchestration ----------------
extern "C" void kernel_launch(void* const* d_in, const int* in_sizes, int n_in,
                              void* d_out, int out_size, void* d_ws, size_t ws_size,
                              hipStream_t stream) {
  const int*   ids      = (const int*)  d_in[0];
  const float* emb      = (const float*)d_in[1];
  const float* ln_w     = (const float*)d_in[2];
  const float* ln_b     = (const float*)d_in[3];
  const float* in_w     = (const float*)d_in[4];
  const float* conv_w   = (const float*)d_in[5];
  const float* conv_b   = (const float*)d_in[6];
  const float* dt_bias  = (const float*)d_in[7];
  const float* A_log    = (const float*)d_in[8];
  const float* Dp       = (const float*)d_in[9];
  const float* rms_w    = (const float*)d_in[10];
  const float* out_w    = (const float*)d_in[11];
  const float* mlp_ln_w = (const float*)d_in[12];
  const float* mlp_ln_b = (const float*)d_in[13];
  const float* w1       = (const float*)d_in[14];
  const float* w2       = (const float*)d_in[15];
  const float* w3       = (const float*)d_in[16];
  const float* normf_w  = (const float*)d_in[17];
  const float* normf_b  = (const float*)d_in[18];
  const float* lm_w     = (const float*)d_in[19];

  char* base = (char*)d_ws;
  size_t off = 0;
  auto alloc = [&](size_t bytes) -> char* {
    char* p = base + off;
    off += (bytes + 255) & ~(size_t)255;
    return p;
  };
  float* h             = (float*)alloc((size_t)TOK * DMODEL * 4);
  unsigned short* xn   = (unsigned short*)alloc((size_t)TOK * DMODEL * 2);
  float* zx            = (float*)alloc((size_t)TOK * DIPAD * 4);
  float* xs            = (float*)alloc((size_t)TOK * DINNER * 4);
  float* Bm            = (float*)alloc((size_t)TOK * DSTATE * 4);
  float* Cm            = (float*)alloc((size_t)TOK * DSTATE * 4);
  float* dtv           = (float*)alloc((size_t)TOK * NHEADS * 4);
  float* dAv           = (float*)alloc((size_t)TOK * NHEADS * 4);
  float* y             = (float*)alloc((size_t)TOK * DINNER * 4);
  unsigned short* ybf  = (unsigned short*)alloc((size_t)TOK * DINNER * 2);
  float* hf            = (float*)alloc((size_t)TOK * DMODEL * 4);
  unsigned short* gbf  = (unsigned short*)alloc((size_t)TOK * DMODEL * 2);
  unsigned short* gate = (unsigned short*)alloc((size_t)TOK * DFF * 2);
  float* Sloc          = (float*)alloc((size_t)2 * NHEADS * NCHUNK * HEADD * DSTATE * 4);
  float* cumv          = (float*)alloc((size_t)2 * NHEADS * SEQL * 4);
  float* Cpart         = (float*)alloc((size_t)2 * TOK * DMODEL * 4);
  unsigned short* inw_bf  = (unsigned short*)alloc((size_t)NLAYER * DIPAD * DMODEL * 2);
  unsigned short* outw_bf = (unsigned short*)alloc((size_t)NLAYER * DMODEL * DINNER * 2);
  unsigned short* w12_bf  = (unsigned short*)alloc((size_t)NLAYER * 2 * DFF * DMODEL * 2);
  unsigned short* w3_bf   = (unsigned short*)alloc((size_t)NLAYER * DMODEL * DFF * 2);
  unsigned short* lm_bf   = (unsigned short*)alloc((size_t)VOCABN * DMODEL * 2);
  if (off > ws_size) return;

  cvt_inw_k<<<NLAYER * DIPAD, 256, 0, stream>>>(in_w, inw_bf);
  cvt_w12_k<<<NLAYER * 2 * DFF, 256, 0, stream>>>(w1, w2, w12_bf);
  {
    const long n1 = (long)NLAYER * DMODEL * DINNER;
    cvt_k<<<(unsigned)((n1 + 1023) / 1024), 256, 0, stream>>>(out_w, outw_bf, n1);
    const long n3 = (long)NLAYER * DMODEL * DFF;
    cvt_k<<<(unsigned)((n3 + 1023) / 1024), 256, 0, stream>>>(w3, w3_bf, n3);
    const long n4 = (long)VOCABN * DMODEL;
    cvt_k<<<(unsigned)((n4 + 1023) / 1024), 256, 0, stream>>>(lm_w, lm_bf, n4);
  }

  embed_k<<<TOK, 192, 0, stream>>>(ids, emb, h);
  ln_k<<<TOK, 192, 0, stream>>>(h, ln_w, ln_b, xn);  // layer-0 pre-norm

  for (int l = 0; l < NLAYER; ++l) {
    gemm_bt<0, 256, 128><<<(TOK / 256) * (DIPAD / 128), 256, 0, stream>>>(
        xn, inw_bf + (size_t)l * DIPAD * DMODEL, zx, nullptr, nullptr, TOK, DIPAD, DMODEL);
    conv_k<<<TOK / CTS, 448, 0, stream>>>(zx, conv_w + (size_t)l * CONVD * 4, conv_b + (size_t)l * CONVD,
                                          dt_bias + l * NHEADS, A_log + l * NHEADS, xs, Bm, Cm, dtv, dAv);
    scan1_k<<<dim3(4, NHEADS, 2 * NCHUNK), 256, 0, stream>>>(xs, Bm, Cm, dtv, dAv, Dp + l * NHEADS, y, Sloc, cumv);
    scan3_k<<<dim3(4, NHEADS, 2 * (NCHUNK - 1)), 256, 0, stream>>>(Cm, cumv, Sloc, y);
    grms_k<<<TOK, 384, 0, stream>>>(y, zx, rms_w + (size_t)l * DINNER, ybf);
    gemm_bt<4, 128, 64><<<2 * (TOK / 128) * (DMODEL / 64), 256, 0, stream>>>(
        ybf, outw_bf + (size_t)l * DMODEL * DINNER, Cpart, nullptr, nullptr, TOK, DMODEL, DINNER);
    // fused join + MLP pre-norm: hf = P0+P1+h, gbf = LN(hf)
    redln_k<<<TOK, 192, 0, stream>>>(Cpart, h, hf, mlp_ln_w + l * DMODEL, mlp_ln_b + l * DMODEL, gbf);
    gemm_bt<2, 256, 128><<<(TOK / 256) * (2 * DFF / 128), 256, 0, stream>>>(
        gbf, w12_bf + (size_t)l * 2 * DFF * DMODEL, nullptr, gate, nullptr, TOK, 2 * DFF, DMODEL);
    gemm_bt<4, 128, 64><<<2 * (TOK / 128) * (DMODEL / 64), 256, 0, stream>>>(
        gate, w3_bf + (size_t)l * DMODEL * DFF, Cpart, nullptr, nullptr, TOK, DMODEL, DFF);
    // fused join + next-layer pre-norm (or final norm): h = P0+P1+hf, xn = LN(h)
    const float* nw = (l + 1 < NLAYER) ? (ln_w + (size_t)(l + 1) * DMODEL) : normf_w;
    const float* nb = (l + 1 < NLAYER) ? (ln_b + (size_t)(l + 1) * DMODEL) : normf_b;
    redln_k<<<TOK, 192, 0, stream>>>(Cpart, hf, h, nw, nb, xn);
  }

  gemm_bt<3, 256, 128><<<(TOK / 256) * (VOCABN / 128), 256, 0, stream>>>(
      xn, lm_bf, (float*)d_out, nullptr, nullptr, TOK, VOCABN, DMODEL);
}